// Round 8
// baseline (213.556 us; speedup 1.0000x reference)
//
#include <hip/hip_runtime.h>

#define B_ 2
#define L_ 2048
#define H_ 1024
#define NH_ 16
#define HD_ 64

using short8 = __attribute__((__ext_vector_type__(8))) short;
using f32x4 = __attribute__((__ext_vector_type__(4))) float;
using f32x16 = __attribute__((__ext_vector_type__(16))) float;
typedef unsigned short u16;
typedef unsigned int u32;

__device__ __forceinline__ u16 f2bf(float f) {
  union { float f; unsigned u; } x{f};
  unsigned u = x.u;
  u = u + 0x7FFFu + ((u >> 16) & 1u);  // round-to-nearest-even
  return (u16)(u >> 16);
}

__device__ __forceinline__ void gld16(const void* g, void* l) {
  __builtin_amdgcn_global_load_lds(
      (const __attribute__((address_space(1))) void*)g,
      (__attribute__((address_space(3))) void*)l, 16, 0, 0);
}

#define MFMA16(a, b, c) __builtin_amdgcn_mfma_f32_16x16x32_bf16((a), (b), (c), 0, 0, 0)
#define MFMA32(a, b, c) __builtin_amdgcn_mfma_f32_32x32x16_bf16((a), (b), (c), 0, 0, 0)

// ---------------- fused cast: hs|Wq|Wk|Wv|Wo -> bf16 (contiguous dst), delta prescale ----------------
__global__ void cast_all(const float* __restrict__ hs, const float* __restrict__ Wq,
                         const float* __restrict__ Wk, const float* __restrict__ Wv,
                         const float* __restrict__ Wo, const float* __restrict__ delta,
                         u16* __restrict__ dst, float* __restrict__ dsc) {
  const int t = blockIdx.x * 256 + threadIdx.x;
  const int i = t * 4;
  const float* src;
  int off;
  if (i < 4194304) {
    src = hs; off = i;
  } else {
    const int j = i - 4194304;
    const int w = j >> 20;
    off = j & 1048575;
    src = (w == 0) ? Wq : (w == 1) ? Wk : (w == 2) ? Wv : Wo;
  }
  float4 v = *(const float4*)(src + off);
  *(ushort4*)(dst + i) = make_ushort4(f2bf(v.x), f2bf(v.y), f2bf(v.z), f2bf(v.w));
  if (t < 4096) dsc[t] = delta[t] * 0.18033688011112042f;  // 0.125*log2(e)
}

// ---------------- QKV GEMM, 256x256 tile, counted-vmcnt pipeline ----------------
__global__ __launch_bounds__(512) void gemm_qkv256(
    const u16* __restrict__ A, const u16* __restrict__ W,
    const float* __restrict__ bq, const float* __restrict__ bk, const float* __restrict__ bv,
    const float* __restrict__ tau,
    u16* __restrict__ qg, u16* __restrict__ kg, u16* __restrict__ vTg) {
  __shared__ u16 As[2][256 * 64];
  __shared__ u16 Bs[2][256 * 64];
  const int tid = threadIdx.x;
  const int lane = tid & 63;
  const int wid = tid >> 6;
  const int wr = wid >> 2;   // 0..1 -> rows wr*128..+128
  const int wc = wid & 3;    // 0..3 -> cols wc*64..+64
  // bijective XCD swizzle: 192 blocks -> 24 consecutive per XCD (W-panel locality)
  const int orig = blockIdx.y * 12 + blockIdx.x;
  const int wg = (orig & 7) * 24 + (orig >> 3);
  const int m0 = (wg & 15) * 256;
  const int n0 = (wg >> 4) * 256;

  const int srow = tid >> 3;          // 0..63 within each li group
  const int sg = tid & 7;             // dest granule

#define STAGE256(slot, t_)                                                              \
  {                                                                                     \
    const int kt64 = (t_) * 64;                                                         \
    _Pragma("unroll") for (int li = 0; li < 4; li++) {                                  \
      const int row = li * 64 + srow;                                                   \
      const int gsrc = sg ^ (row & 7);                                                  \
      gld16(A + (size_t)(m0 + row) * 1024 + kt64 + gsrc * 8,                            \
            (char*)As[slot] + li * 8192 + wid * 1024 + lane * 16);                      \
      gld16(W + (size_t)(n0 + row) * 1024 + kt64 + gsrc * 8,                            \
            (char*)Bs[slot] + li * 8192 + wid * 1024 + lane * 16);                      \
    }                                                                                   \
  }

  f32x4 acc[8][4] = {};

  STAGE256(0, 0);
  STAGE256(1, 1);

  for (int t = 0; t < 16; t++) {
    if (t >= 1 && t + 1 < 16) STAGE256((t + 1) & 1, t + 1);
    if (t + 1 < 16) {
      asm volatile("s_waitcnt vmcnt(8)" ::: "memory");
    } else {
      asm volatile("s_waitcnt vmcnt(0)" ::: "memory");
    }
    asm volatile("s_barrier" ::: "memory");
    const u16* Ab = As[t & 1];
    const u16* Bb = Bs[t & 1];
    short8 bf[4];
#pragma unroll
    for (int q = 0; q < 4; q++) {
      const int mh = q & 1, ks = q >> 1;
      const int g0 = ks * 4 + (lane >> 4);
      if (mh == 0) {
#pragma unroll
        for (int ni = 0; ni < 4; ni++) {
          const int r = wc * 64 + ni * 16 + (lane & 15);
          bf[ni] = *(const short8*)((const char*)Bb + r * 128 + ((g0 ^ (r & 7)) << 4));
        }
      }
      short8 af[4];
#pragma unroll
      for (int mi = 0; mi < 4; mi++) {
        const int r = wr * 128 + (mh * 4 + mi) * 16 + (lane & 15);
        af[mi] = *(const short8*)((const char*)Ab + r * 128 + ((g0 ^ (r & 7)) << 4));
      }
      __builtin_amdgcn_s_setprio(1);
#pragma unroll
      for (int mi = 0; mi < 4; mi++)
#pragma unroll
        for (int ni = 0; ni < 4; ni++)
          acc[mh * 4 + mi][ni] = MFMA16(af[mi], bf[ni], acc[mh * 4 + mi][ni]);
      __builtin_amdgcn_s_setprio(0);
      asm volatile("s_barrier" ::: "memory");
    }
  }

  const int which = n0 >> 10;  // 0=q 1=k 2=v, uniform per block (1024/256=4 blocks each)
  const int b_blk = m0 >> 11;
  const float scl = (which == 0) ? tau[b_blk] * 0.18033688011112042f : 1.0f;
  const float* bias = which == 0 ? bq : (which == 1 ? bk : bv);
#pragma unroll
  for (int ni = 0; ni < 4; ni++) {
    const int n = n0 + wc * 64 + ni * 16 + (lane & 15);
    const int nn = n & 1023;
    const int h = nn >> 6, d = nn & 63;
    const float bb = bias[nn];
#pragma unroll
    for (int mi = 0; mi < 8; mi++) {
      const int mb = m0 + wr * 128 + mi * 16 + ((lane >> 4) << 2);
      const int b = mb >> 11;
      const int lq = mb & 2047;
      if (which == 2) {
        ushort4 pk = make_ushort4(f2bf(acc[mi][ni][0] + bb), f2bf(acc[mi][ni][1] + bb),
                                  f2bf(acc[mi][ni][2] + bb), f2bf(acc[mi][ni][3] + bb));
        *(ushort4*)&vTg[((size_t)(b * NH_ + h) * HD_ + d) * L_ + lq] = pk;
      } else {
        u16* dst = which == 0 ? qg : kg;
#pragma unroll
        for (int r = 0; r < 4; r++)
          dst[((size_t)(b * NH_ + h) * L_ + lq + r) * HD_ + d] = f2bf((acc[mi][ni][r] + bb) * scl);
      }
    }
  }
}

// ---------------- flash attention: 1-wave self-paced, K/V direct L2->reg ----------------
// grid 2048 x 64 thr; each wave owns 32 q-rows x all 2048 keys; no LDS staging, no barriers.
// K/V double-buffered in registers one 32-key tile ahead (T14).
__global__ __launch_bounds__(64) void attn(
    const u16* __restrict__ qg, const u16* __restrict__ kg, const u16* __restrict__ vTg,
    const float* __restrict__ dsc, u16* __restrict__ ctxg) {
  __shared__ u16 tw[2048];  // 4KB epilogue transpose tile
  const int lane = threadIdx.x;
  const int lane31 = lane & 31;
  const int hi = lane >> 5;
  // bijective XCD-chunk swizzle: 2048 blocks -> 256 consecutive wgids (4 bh) per XCD
  const int orig = blockIdx.x;
  const int wgid = (orig & 7) * 256 + (orig >> 3);
  const int bh = wgid >> 6;
  const int qblk = wgid & 63;
  const int b = bh >> 4;
  const int h = bh & 15;
  const int q0 = qblk * 32;
  const u16* qb = qg + (size_t)bh * L_ * HD_;
  const u16* kb = kg + (size_t)bh * L_ * HD_;
  const u16* vb = vTg + (size_t)bh * HD_ * L_;
  const float* db = dsc + (size_t)b * L_;

  // Q fragments (B-operand): lane holds Q[q0+lane31][ks*16 + hi*8 .. +7]
  short8 qf[4];
#pragma unroll
  for (int ks = 0; ks < 4; ks++)
    qf[ks] = *(const short8*)&qb[(size_t)(q0 + lane31) * 64 + ks * 16 + hi * 8];

  f32x16 acc[2] = {};  // ctx^T: [dtile] rows d=crow(r,hi), col q=lane31
  float mrun = -__builtin_inff(), lrun = 0.f;

// load K/V fragments for 32-key tile t into register sets
#define LOADT(kf, vf, t_)                                                                \
  {                                                                                      \
    const int j = (t_) * 32;                                                             \
    _Pragma("unroll") for (int ks = 0; ks < 4; ks++)                                     \
        kf[ks] = *(const short8*)&kb[(size_t)(j + lane31) * 64 + ks * 16 + hi * 8];      \
    _Pragma("unroll") for (int i = 0; i < 4; i++) {                                      \
      const int dt = i >> 1, ks2 = i & 1;                                                \
      vf[i] = *(const short8*)&vb[(size_t)(dt * 32 + lane31) * L_ + j + ks2 * 16 + hi * 8]; \
    }                                                                                    \
  }

// process one 32-key tile using register K/V
#define TILE(kf, vf, t_)                                                                 \
  {                                                                                      \
    const int j = (t_) * 32;                                                             \
    f32x16 s = {};                                                                       \
    __builtin_amdgcn_s_setprio(1);                                                       \
    _Pragma("unroll") for (int ks = 0; ks < 4; ks++) s = MFMA32(kf[ks], qf[ks], s);      \
    __builtin_amdgcn_s_setprio(0);                                                       \
    float sv[16];                                                                        \
    _Pragma("unroll") for (int g = 0; g < 4; g++) {                                      \
      float4 dl = *(const float4*)&db[j + g * 8 + hi * 4];                               \
      sv[g * 4 + 0] = s[g * 4 + 0] + dl.x;                                               \
      sv[g * 4 + 1] = s[g * 4 + 1] + dl.y;                                               \
      sv[g * 4 + 2] = s[g * 4 + 2] + dl.z;                                               \
      sv[g * 4 + 3] = s[g * 4 + 3] + dl.w;                                               \
    }                                                                                    \
    float t0 = fmaxf(fmaxf(sv[0], sv[1]), fmaxf(sv[2], sv[3]));                          \
    float t1 = fmaxf(fmaxf(sv[4], sv[5]), fmaxf(sv[6], sv[7]));                          \
    float t2 = fmaxf(fmaxf(sv[8], sv[9]), fmaxf(sv[10], sv[11]));                        \
    float t3 = fmaxf(fmaxf(sv[12], sv[13]), fmaxf(sv[14], sv[15]));                      \
    float pmax = fmaxf(fmaxf(t0, t1), fmaxf(t2, t3));                                    \
    pmax = fmaxf(pmax, __shfl_xor(pmax, 32));                                            \
    if (!__all(pmax - mrun <= 11.5f)) {                                                  \
      float mnew = fmaxf(mrun, pmax);                                                    \
      float al = __builtin_amdgcn_exp2f(mrun - mnew);                                    \
      mrun = mnew;                                                                       \
      lrun *= al;                                                                        \
      _Pragma("unroll") for (int dt = 0; dt < 2; dt++)                                   \
          _Pragma("unroll") for (int r = 0; r < 16; r++) acc[dt][r] *= al;               \
    }                                                                                    \
    float p[16];                                                                         \
    _Pragma("unroll") for (int r = 0; r < 16; r++)                                       \
        p[r] = __builtin_amdgcn_exp2f(sv[r] - mrun);                                     \
    float r0 = (p[0] + p[1]) + (p[2] + p[3]);                                            \
    float r1 = (p[4] + p[5]) + (p[6] + p[7]);                                            \
    float r2 = (p[8] + p[9]) + (p[10] + p[11]);                                          \
    float r3 = (p[12] + p[13]) + (p[14] + p[15]);                                        \
    float rs = (r0 + r1) + (r2 + r3);                                                    \
    rs += __shfl_xor(rs, 32);                                                            \
    lrun += rs;                                                                          \
    u32 pk[8];                                                                           \
    _Pragma("unroll") for (int i = 0; i < 8; i++)                                        \
        asm("v_cvt_pk_bf16_f32 %0, %1, %2" : "=v"(pk[i]) : "v"(p[2 * i]), "v"(p[2 * i + 1])); \
    asm volatile("v_permlane32_swap_b32 %0, %1" : "+v"(pk[0]), "+v"(pk[2]));             \
    asm volatile("v_permlane32_swap_b32 %0, %1" : "+v"(pk[1]), "+v"(pk[3]));             \
    asm volatile("v_permlane32_swap_b32 %0, %1" : "+v"(pk[4]), "+v"(pk[6]));             \
    asm volatile("v_permlane32_swap_b32 %0, %1" : "+v"(pk[5]), "+v"(pk[7]));             \
    union U8 { u32 u[4]; short8 s; } f0, f1;                                             \
    f0.u[0] = pk[0]; f0.u[1] = pk[1]; f0.u[2] = pk[2]; f0.u[3] = pk[3];                  \
    f1.u[0] = pk[4]; f1.u[1] = pk[5]; f1.u[2] = pk[6]; f1.u[3] = pk[7];                  \
    __builtin_amdgcn_s_setprio(1);                                                       \
    _Pragma("unroll") for (int ks2 = 0; ks2 < 2; ks2++) {                                \
      short8 pf = ks2 ? f1.s : f0.s;                                                     \
      _Pragma("unroll") for (int dt = 0; dt < 2; dt++)                                   \
          acc[dt] = MFMA32(vf[dt * 2 + ks2], pf, acc[dt]);                               \
    }                                                                                    \
    __builtin_amdgcn_s_setprio(0);                                                       \
  }

  short8 kA[4], vA[4], kB[4], vB[4];
  LOADT(kA, vA, 0);
  for (int t = 0; t < 64; t += 2) {
    LOADT(kB, vB, t + 1);
    TILE(kA, vA, t);
    if (t + 2 < 64) LOADT(kA, vA, t + 2);
    TILE(kB, vB, t + 1);
  }

  // epilogue: transpose ctx^T -> ctx via swizzled LDS tile, coalesced store
  const float inv = 1.0f / lrun;
#pragma unroll
  for (int dt = 0; dt < 2; dt++)
#pragma unroll
    for (int g = 0; g < 4; g++) {
      ushort4 w4 = make_ushort4(f2bf(acc[dt][g * 4 + 0] * inv), f2bf(acc[dt][g * 4 + 1] * inv),
                                f2bf(acc[dt][g * 4 + 2] * inv), f2bf(acc[dt][g * 4 + 3] * inv));
      const int d0 = dt * 32 + g * 8 + hi * 4;
      const int byte = (lane31 * 128 + d0 * 2) ^ ((lane31 & 15) << 3);
      *(ushort4*)((char*)tw + byte) = w4;
    }
  asm volatile("s_waitcnt lgkmcnt(0)" ::: "memory");
  const size_t obase = ((size_t)b * L_ + q0) * 1024 + h * 64;
#pragma unroll
  for (int i = 0; i < 16; i++) {
    const int qr = 2 * i + hi;
    const int byte = (qr * 128 + lane31 * 4) ^ ((qr & 15) << 3);
    const u32 val = *(const u32*)((const char*)tw + byte);
    *(u32*)&ctxg[obase + (size_t)qr * 1024 + lane31 * 2] = val;
  }
}

// ---------------- output GEMM: ctx[4096,1024] x Wo[1024,1024]^T + bo -> f32 ----------------
__global__ __launch_bounds__(256) void gemm_out(
    const u16* __restrict__ A, const u16* __restrict__ W,
    const float* __restrict__ bo, float* __restrict__ out) {
  __shared__ u16 As[128 * 64];
  __shared__ u16 Bs[128 * 64];
  const int tid = threadIdx.x;
  const int lane = tid & 63;
  const int wave = tid >> 6;
  const int wrow = (wave >> 1) * 64;
  const int wcol = (wave & 1) * 64;
  const int m0 = blockIdx.y * 128;
  const int n0 = blockIdx.x * 128;
  const int rr = tid >> 3;
  const int c8 = (tid & 7) * 8;
  f32x4 acc[4][4] = {};
  for (int kt = 0; kt < 1024; kt += 64) {
#pragma unroll
    for (int i = 0; i < 4; i++) {
      gld16(A + (size_t)(m0 + i * 32 + rr) * 1024 + kt + c8, (char*)As + i * 4096 + wave * 1024);
      gld16(W + (size_t)(n0 + i * 32 + rr) * 1024 + kt + c8, (char*)Bs + i * 4096 + wave * 1024);
    }
    __syncthreads();
#pragma unroll
    for (int kc = 0; kc < 2; kc++) {
      const int ko = kc * 32 + (lane >> 4) * 8;
      short8 af[4], bf[4];
#pragma unroll
      for (int mi = 0; mi < 4; mi++)
        af[mi] = *(const short8*)&As[(wrow + mi * 16 + (lane & 15)) * 64 + ko];
#pragma unroll
      for (int ni = 0; ni < 4; ni++)
        bf[ni] = *(const short8*)&Bs[(wcol + ni * 16 + (lane & 15)) * 64 + ko];
#pragma unroll
      for (int mi = 0; mi < 4; mi++)
#pragma unroll
        for (int ni = 0; ni < 4; ni++)
          acc[mi][ni] = MFMA16(af[mi], bf[ni], acc[mi][ni]);
    }
    __syncthreads();
  }
#pragma unroll
  for (int ni = 0; ni < 4; ni++) {
    const int n = n0 + wcol + ni * 16 + (lane & 15);
    const float bb = bo[n];
#pragma unroll
    for (int mi = 0; mi < 4; mi++) {
      const int mb = m0 + wrow + mi * 16 + ((lane >> 4) << 2);
#pragma unroll
      for (int r = 0; r < 4; r++)
        out[(size_t)(mb + r) * 1024 + n] = acc[mi][ni][r] + bb;
    }
  }
}

extern "C" void kernel_launch(void* const* d_in, const int* in_sizes, int n_in,
                              void* d_out, int out_size, void* d_ws, size_t ws_size,
                              hipStream_t stream) {
  const float* hs = (const float*)d_in[0];
  const float* tau = (const float*)d_in[1];
  const float* delta = (const float*)d_in[2];
  const float* Wq = (const float*)d_in[3];
  const float* bq = (const float*)d_in[4];
  const float* Wk = (const float*)d_in[5];
  const float* bk = (const float*)d_in[6];
  const float* Wv = (const float*)d_in[7];
  const float* bv = (const float*)d_in[8];
  const float* Wo = (const float*)d_in[9];
  const float* bo = (const float*)d_in[10];
  float* out = (float*)d_out;

  u16* ws = (u16*)d_ws;
  u16* hsb  = ws;                   // 4194304
  u16* wqkv = ws + 4194304;         // 3145728 (Wq|Wk|Wv)
  u16* wob  = ws + 7340032;         // 1048576
  u16* qg   = ws + 8388608;         // 4194304
  u16* kg   = ws + 12582912;        // 4194304
  u16* vTg  = ws + 16777216;        // 4194304
  u16* ctxg = ws + 20971520;        // 4194304
  float* dsc = (float*)(ws + 25165824);  // 4096 floats

  cast_all<<<8192, 256, 0, stream>>>(hs, Wq, Wk, Wv, Wo, delta, ws, dsc);

  gemm_qkv256<<<dim3(12, 16), 512, 0, stream>>>(hsb, wqkv, bq, bk, bv, tau, qg, kg, vTg);
  attn<<<2048, 64, 0, stream>>>(qg, kg, vTg, dsc, ctxg);
  gemm_out<<<dim3(8, 32), 256, 0, stream>>>(ctxg, wob, bo, out);
}

// Round 9
// 150.405 us; speedup vs baseline: 1.4199x; 1.4199x over previous
//
#include <hip/hip_runtime.h>

#define B_ 2
#define L_ 2048
#define H_ 1024
#define NH_ 16
#define HD_ 64

using short8 = __attribute__((__ext_vector_type__(8))) short;
using f32x4 = __attribute__((__ext_vector_type__(4))) float;
using f32x16 = __attribute__((__ext_vector_type__(16))) float;
typedef unsigned short u16;
typedef unsigned int u32;

__device__ __forceinline__ u16 f2bf(float f) {
  union { float f; unsigned u; } x{f};
  unsigned u = x.u;
  u = u + 0x7FFFu + ((u >> 16) & 1u);  // round-to-nearest-even
  return (u16)(u >> 16);
}

__device__ __forceinline__ void gld16(const void* g, void* l) {
  __builtin_amdgcn_global_load_lds(
      (const __attribute__((address_space(1))) void*)g,
      (__attribute__((address_space(3))) void*)l, 16, 0, 0);
}

#define MFMA16(a, b, c) __builtin_amdgcn_mfma_f32_16x16x32_bf16((a), (b), (c), 0, 0, 0)
#define MFMA32(a, b, c) __builtin_amdgcn_mfma_f32_32x32x16_bf16((a), (b), (c), 0, 0, 0)

// ---------------- fused cast: hs|Wq|Wk|Wv|Wo -> bf16 (contiguous dst), delta prescale ----------------
__global__ void cast_all(const float* __restrict__ hs, const float* __restrict__ Wq,
                         const float* __restrict__ Wk, const float* __restrict__ Wv,
                         const float* __restrict__ Wo, const float* __restrict__ delta,
                         u16* __restrict__ dst, float* __restrict__ dsc) {
  const int t = blockIdx.x * 256 + threadIdx.x;
  const int i = t * 4;
  const float* src;
  int off;
  if (i < 4194304) {
    src = hs; off = i;
  } else {
    const int j = i - 4194304;
    const int w = j >> 20;
    off = j & 1048575;
    src = (w == 0) ? Wq : (w == 1) ? Wk : (w == 2) ? Wv : Wo;
  }
  float4 v = *(const float4*)(src + off);
  *(ushort4*)(dst + i) = make_ushort4(f2bf(v.x), f2bf(v.y), f2bf(v.z), f2bf(v.w));
  if (t < 4096) dsc[t] = delta[t] * 0.18033688011112042f;  // 0.125*log2(e)
}

// ---------------- QKV GEMM, 256x256 tile, counted-vmcnt pipeline ----------------
__global__ __launch_bounds__(512) void gemm_qkv256(
    const u16* __restrict__ A, const u16* __restrict__ W,
    const float* __restrict__ bq, const float* __restrict__ bk, const float* __restrict__ bv,
    const float* __restrict__ tau,
    u16* __restrict__ qg, u16* __restrict__ kg, u16* __restrict__ vTg) {
  __shared__ u16 As[2][256 * 64];
  __shared__ u16 Bs[2][256 * 64];
  const int tid = threadIdx.x;
  const int lane = tid & 63;
  const int wid = tid >> 6;
  const int wr = wid >> 2;   // 0..1 -> rows wr*128..+128
  const int wc = wid & 3;    // 0..3 -> cols wc*64..+64
  // bijective XCD swizzle: 192 blocks -> 24 consecutive per XCD (W-panel locality)
  const int orig = blockIdx.y * 12 + blockIdx.x;
  const int wg = (orig & 7) * 24 + (orig >> 3);
  const int m0 = (wg & 15) * 256;
  const int n0 = (wg >> 4) * 256;

  const int srow = tid >> 3;          // 0..63 within each li group
  const int sg = tid & 7;             // dest granule

#define STAGE256(slot, t_)                                                              \
  {                                                                                     \
    const int kt64 = (t_) * 64;                                                         \
    _Pragma("unroll") for (int li = 0; li < 4; li++) {                                  \
      const int row = li * 64 + srow;                                                   \
      const int gsrc = sg ^ (row & 7);                                                  \
      gld16(A + (size_t)(m0 + row) * 1024 + kt64 + gsrc * 8,                            \
            (char*)As[slot] + li * 8192 + wid * 1024 + lane * 16);                      \
      gld16(W + (size_t)(n0 + row) * 1024 + kt64 + gsrc * 8,                            \
            (char*)Bs[slot] + li * 8192 + wid * 1024 + lane * 16);                      \
    }                                                                                   \
  }

  f32x4 acc[8][4] = {};

  STAGE256(0, 0);
  STAGE256(1, 1);

  for (int t = 0; t < 16; t++) {
    if (t >= 1 && t + 1 < 16) STAGE256((t + 1) & 1, t + 1);
    if (t + 1 < 16) {
      asm volatile("s_waitcnt vmcnt(8)" ::: "memory");
    } else {
      asm volatile("s_waitcnt vmcnt(0)" ::: "memory");
    }
    asm volatile("s_barrier" ::: "memory");
    const u16* Ab = As[t & 1];
    const u16* Bb = Bs[t & 1];
    short8 bf[4];
#pragma unroll
    for (int q = 0; q < 4; q++) {
      const int mh = q & 1, ks = q >> 1;
      const int g0 = ks * 4 + (lane >> 4);
      if (mh == 0) {
#pragma unroll
        for (int ni = 0; ni < 4; ni++) {
          const int r = wc * 64 + ni * 16 + (lane & 15);
          bf[ni] = *(const short8*)((const char*)Bb + r * 128 + ((g0 ^ (r & 7)) << 4));
        }
      }
      short8 af[4];
#pragma unroll
      for (int mi = 0; mi < 4; mi++) {
        const int r = wr * 128 + (mh * 4 + mi) * 16 + (lane & 15);
        af[mi] = *(const short8*)((const char*)Ab + r * 128 + ((g0 ^ (r & 7)) << 4));
      }
      __builtin_amdgcn_s_setprio(1);
#pragma unroll
      for (int mi = 0; mi < 4; mi++)
#pragma unroll
        for (int ni = 0; ni < 4; ni++)
          acc[mh * 4 + mi][ni] = MFMA16(af[mi], bf[ni], acc[mh * 4 + mi][ni]);
      __builtin_amdgcn_s_setprio(0);
      asm volatile("s_barrier" ::: "memory");
    }
  }

  const int which = n0 >> 10;  // 0=q 1=k 2=v, uniform per block (1024/256=4 blocks each)
  const int b_blk = m0 >> 11;
  const float scl = (which == 0) ? tau[b_blk] * 0.18033688011112042f : 1.0f;
  const float* bias = which == 0 ? bq : (which == 1 ? bk : bv);
#pragma unroll
  for (int ni = 0; ni < 4; ni++) {
    const int n = n0 + wc * 64 + ni * 16 + (lane & 15);
    const int nn = n & 1023;
    const int h = nn >> 6, d = nn & 63;
    const float bb = bias[nn];
#pragma unroll
    for (int mi = 0; mi < 8; mi++) {
      const int mb = m0 + wr * 128 + mi * 16 + ((lane >> 4) << 2);
      const int b = mb >> 11;
      const int lq = mb & 2047;
      if (which == 2) {
        ushort4 pk = make_ushort4(f2bf(acc[mi][ni][0] + bb), f2bf(acc[mi][ni][1] + bb),
                                  f2bf(acc[mi][ni][2] + bb), f2bf(acc[mi][ni][3] + bb));
        *(ushort4*)&vTg[((size_t)(b * NH_ + h) * HD_ + d) * L_ + lq] = pk;
      } else {
        u16* dst = which == 0 ? qg : kg;
#pragma unroll
        for (int r = 0; r < 4; r++)
          dst[((size_t)(b * NH_ + h) * L_ + lq + r) * HD_ + d] = f2bf((acc[mi][ni][r] + bb) * scl);
      }
    }
  }
}

// ---------------- flash attention, swapped-QK^T 32x32x16, 8-wave blocks ----------------
// grid 256 XCD-swizzled; 512 threads (8 waves x 32 q-rows = 256 q-rows/block);
// K/V 64-key tile shared by all 8 waves, double-buffered; 2 gld16 staging per wave.
__global__ __launch_bounds__(512) void attn(
    const u16* __restrict__ qg, const u16* __restrict__ kg, const u16* __restrict__ vTg,
    const float* __restrict__ dsc, u16* __restrict__ ctxg) {
  // per buffer (16KB): 8 K blocks (2 ktile x 4 ks) + 8 V blocks (2 kt x 2 dt x 2 ks2), 1KB each
  __shared__ u16 lds[2][8192];
  const int tid = threadIdx.x;
  const int lane = tid & 63;
  const int wv = tid >> 6;   // 0..7
  const int lane31 = lane & 31;
  const int hi = lane >> 5;
  // bijective XCD-chunk swizzle: nwg=256 -> 32 consecutive wgids (4 bh) per XCD
  const int orig = blockIdx.x;
  const int wgid = (orig & 7) * 32 + (orig >> 3);
  const int bh = wgid >> 3;
  const int qblk = wgid & 7;
  const int b = bh >> 4;
  const int h = bh & 15;
  const int q0 = qblk * 256 + wv * 32;
  const u16* qb = qg + (size_t)bh * L_ * HD_;
  const u16* kb = kg + (size_t)bh * L_ * HD_;
  const u16* vb = vTg + (size_t)bh * HD_ * L_;
  const float* db = dsc + (size_t)b * L_;

  // Q fragments (B-operand): lane holds Q[q0+lane31][ks*16 + hi*8 .. +7]
  short8 qf[4];
#pragma unroll
  for (int ks = 0; ks < 4; ks++)
    qf[ks] = *(const short8*)&qb[(size_t)(q0 + lane31) * 64 + ks * 16 + hi * 8];

  // ones A-fragment: row d=0 all-ones -> l accumulates in acc_l row 0
  union { u32 u[4]; short8 s; } onesu;
  const u32 ow = (lane31 == 0) ? 0x3F803F80u : 0u;
  onesu.u[0] = ow; onesu.u[1] = ow; onesu.u[2] = ow; onesu.u[3] = ow;
  const short8 onesf = onesu.s;

  f32x16 acc[2] = {};   // ctx^T: [dtile] rows d=crow(r,hi), col q=lane31
  f32x16 accl = {};     // row 0 = running softmax denominator per q
  float mrun = -__builtin_inff();

  // staging: wave wv stages K block wv and V block wv (1 KB each)
#define STAGE(bufi, j0)                                                                   \
  {                                                                                       \
    u16* bp = lds[bufi];                                                                  \
    {                                                                                     \
      const int kt = wv >> 2, ks = wv & 3;                                                \
      gld16(kb + (size_t)((j0) + kt * 32 + lane31) * 64 + ks * 16 + hi * 8,               \
            bp + wv * 512 + lane * 8);                                                    \
    }                                                                                     \
    {                                                                                     \
      const int kt = wv >> 2, dt = (wv >> 1) & 1, ks2 = wv & 1;                           \
      gld16(vb + (size_t)(dt * 32 + lane31) * L_ + (j0) + kt * 32 + ks2 * 16 + hi * 8,    \
            bp + (8 + wv) * 512 + lane * 8);                                              \
    }                                                                                     \
  }

  STAGE(0, 0);
  __syncthreads();
  int cur = 0;
  for (int jt = 0; jt < L_ / 64; jt++) {
    const int j0 = jt * 64;
    if (jt + 1 < L_ / 64) STAGE(cur ^ 1, j0 + 64);
    const u16* bp = lds[cur];
#pragma unroll
    for (int kt = 0; kt < 2; kt++) {
      // S^T = K . Q^T : lane holds col q=lane31, rows key=crow(r,hi)
      f32x16 s = {};
      __builtin_amdgcn_s_setprio(1);
#pragma unroll
      for (int ks = 0; ks < 4; ks++) {
        short8 kf = *(const short8*)&bp[(kt * 4 + ks) * 512 + lane * 8];
        s = MFMA32(kf, qf[ks], s);
      }
      __builtin_amdgcn_s_setprio(0);
      // add pre-scaled delta (log2 units)
      float sv[16];
#pragma unroll
      for (int g = 0; g < 4; g++) {
        float4 dl = *(const float4*)&db[j0 + kt * 32 + g * 8 + hi * 4];
        sv[g * 4 + 0] = s[g * 4 + 0] + dl.x;
        sv[g * 4 + 1] = s[g * 4 + 1] + dl.y;
        sv[g * 4 + 2] = s[g * 4 + 2] + dl.z;
        sv[g * 4 + 3] = s[g * 4 + 3] + dl.w;
      }
      // row max (15 local + 1 cross-half shuffle)
      float t0 = fmaxf(fmaxf(sv[0], sv[1]), fmaxf(sv[2], sv[3]));
      float t1 = fmaxf(fmaxf(sv[4], sv[5]), fmaxf(sv[6], sv[7]));
      float t2 = fmaxf(fmaxf(sv[8], sv[9]), fmaxf(sv[10], sv[11]));
      float t3 = fmaxf(fmaxf(sv[12], sv[13]), fmaxf(sv[14], sv[15]));
      float pmax = fmaxf(fmaxf(t0, t1), fmaxf(t2, t3));
      pmax = fmaxf(pmax, __shfl_xor(pmax, 32));
      // defer-max (THR = 8 * log2e ~ 11.54)
      if (!__all(pmax - mrun <= 11.5f)) {
        float mnew = fmaxf(mrun, pmax);
        float al = __builtin_amdgcn_exp2f(mrun - mnew);
        mrun = mnew;
        accl[0] *= al;
#pragma unroll
        for (int dt = 0; dt < 2; dt++)
#pragma unroll
          for (int r = 0; r < 16; r++) acc[dt][r] *= al;
      }
      float p[16];
#pragma unroll
      for (int r = 0; r < 16; r++) p[r] = __builtin_amdgcn_exp2f(sv[r] - mrun);
      // T12: pack to bf16 pairs, permlane32_swap to build PV B-fragments in-register
      u32 pk[8];
#pragma unroll
      for (int i = 0; i < 8; i++)
        asm("v_cvt_pk_bf16_f32 %0, %1, %2" : "=v"(pk[i]) : "v"(p[2 * i]), "v"(p[2 * i + 1]));
      asm volatile("v_permlane32_swap_b32 %0, %1" : "+v"(pk[0]), "+v"(pk[2]));
      asm volatile("v_permlane32_swap_b32 %0, %1" : "+v"(pk[1]), "+v"(pk[3]));
      asm volatile("v_permlane32_swap_b32 %0, %1" : "+v"(pk[4]), "+v"(pk[6]));
      asm volatile("v_permlane32_swap_b32 %0, %1" : "+v"(pk[5]), "+v"(pk[7]));
      union U8 { u32 u[4]; short8 s; } f0, f1;
      f0.u[0] = pk[0]; f0.u[1] = pk[1]; f0.u[2] = pk[2]; f0.u[3] = pk[3];
      f1.u[0] = pk[4]; f1.u[1] = pk[5]; f1.u[2] = pk[6]; f1.u[3] = pk[7];
      // ctx^T += V^T . P ; accl += ones_row0 . P (softmax denominator via MFMA)
      __builtin_amdgcn_s_setprio(1);
#pragma unroll
      for (int ks2 = 0; ks2 < 2; ks2++) {
        short8 pf = ks2 ? f1.s : f0.s;
#pragma unroll
        for (int dt = 0; dt < 2; dt++) {
          short8 vf = *(const short8*)&bp[(8 + kt * 4 + dt * 2 + ks2) * 512 + lane * 8];
          acc[dt] = MFMA32(vf, pf, acc[dt]);
        }
        accl = MFMA32(onesf, pf, accl);
      }
      __builtin_amdgcn_s_setprio(0);
    }
    __syncthreads();
    cur ^= 1;
  }

  // epilogue: transpose ctx^T -> ctx via swizzled per-wave LDS tile, coalesced store
  __syncthreads();
  u16* tw = (u16*)lds + wv * 2048;  // 4KB per wave: [32 q][64 d] bf16, XOR-swizzled
  const float l0 = accl[0];
  const float l1 = __shfl_xor(l0, 32);
  const float inv = 1.0f / (hi ? l1 : l0);
#pragma unroll
  for (int dt = 0; dt < 2; dt++)
#pragma unroll
    for (int g = 0; g < 4; g++) {
      ushort4 w4 = make_ushort4(f2bf(acc[dt][g * 4 + 0] * inv), f2bf(acc[dt][g * 4 + 1] * inv),
                                f2bf(acc[dt][g * 4 + 2] * inv), f2bf(acc[dt][g * 4 + 3] * inv));
      const int d0 = dt * 32 + g * 8 + hi * 4;
      const int byte = (lane31 * 128 + d0 * 2) ^ ((lane31 & 15) << 3);
      *(ushort4*)((char*)tw + byte) = w4;
    }
  asm volatile("s_waitcnt lgkmcnt(0)" ::: "memory");
  const size_t obase = ((size_t)b * L_ + q0) * 1024 + h * 64;
#pragma unroll
  for (int i = 0; i < 16; i++) {
    const int qr = 2 * i + hi;
    const int byte = (qr * 128 + lane31 * 4) ^ ((qr & 15) << 3);
    const u32 val = *(const u32*)((const char*)tw + byte);
    *(u32*)&ctxg[obase + (size_t)qr * 1024 + lane31 * 2] = val;
  }
}

// ---------------- output GEMM: ctx[4096,1024] x Wo[1024,1024]^T + bo -> f32 ----------------
__global__ __launch_bounds__(256) void gemm_out(
    const u16* __restrict__ A, const u16* __restrict__ W,
    const float* __restrict__ bo, float* __restrict__ out) {
  __shared__ u16 As[128 * 64];
  __shared__ u16 Bs[128 * 64];
  const int tid = threadIdx.x;
  const int lane = tid & 63;
  const int wave = tid >> 6;
  const int wrow = (wave >> 1) * 64;
  const int wcol = (wave & 1) * 64;
  const int m0 = blockIdx.y * 128;
  const int n0 = blockIdx.x * 128;
  const int rr = tid >> 3;
  const int c8 = (tid & 7) * 8;
  f32x4 acc[4][4] = {};
  for (int kt = 0; kt < 1024; kt += 64) {
#pragma unroll
    for (int i = 0; i < 4; i++) {
      gld16(A + (size_t)(m0 + i * 32 + rr) * 1024 + kt + c8, (char*)As + i * 4096 + wave * 1024);
      gld16(W + (size_t)(n0 + i * 32 + rr) * 1024 + kt + c8, (char*)Bs + i * 4096 + wave * 1024);
    }
    __syncthreads();
#pragma unroll
    for (int kc = 0; kc < 2; kc++) {
      const int ko = kc * 32 + (lane >> 4) * 8;
      short8 af[4], bf[4];
#pragma unroll
      for (int mi = 0; mi < 4; mi++)
        af[mi] = *(const short8*)&As[(wrow + mi * 16 + (lane & 15)) * 64 + ko];
#pragma unroll
      for (int ni = 0; ni < 4; ni++)
        bf[ni] = *(const short8*)&Bs[(wcol + ni * 16 + (lane & 15)) * 64 + ko];
#pragma unroll
      for (int mi = 0; mi < 4; mi++)
#pragma unroll
        for (int ni = 0; ni < 4; ni++)
          acc[mi][ni] = MFMA16(af[mi], bf[ni], acc[mi][ni]);
    }
    __syncthreads();
  }
#pragma unroll
  for (int ni = 0; ni < 4; ni++) {
    const int n = n0 + wcol + ni * 16 + (lane & 15);
    const float bb = bo[n];
#pragma unroll
    for (int mi = 0; mi < 4; mi++) {
      const int mb = m0 + wrow + mi * 16 + ((lane >> 4) << 2);
#pragma unroll
      for (int r = 0; r < 4; r++)
        out[(size_t)(mb + r) * 1024 + n] = acc[mi][ni][r] + bb;
    }
  }
}

extern "C" void kernel_launch(void* const* d_in, const int* in_sizes, int n_in,
                              void* d_out, int out_size, void* d_ws, size_t ws_size,
                              hipStream_t stream) {
  const float* hs = (const float*)d_in[0];
  const float* tau = (const float*)d_in[1];
  const float* delta = (const float*)d_in[2];
  const float* Wq = (const float*)d_in[3];
  const float* bq = (const float*)d_in[4];
  const float* Wk = (const float*)d_in[5];
  const float* bk = (const float*)d_in[6];
  const float* Wv = (const float*)d_in[7];
  const float* bv = (const float*)d_in[8];
  const float* Wo = (const float*)d_in[9];
  const float* bo = (const float*)d_in[10];
  float* out = (float*)d_out;

  u16* ws = (u16*)d_ws;
  u16* hsb  = ws;                   // 4194304
  u16* wqkv = ws + 4194304;         // 3145728 (Wq|Wk|Wv)
  u16* wob  = ws + 7340032;         // 1048576
  u16* qg   = ws + 8388608;         // 4194304
  u16* kg   = ws + 12582912;        // 4194304
  u16* vTg  = ws + 16777216;        // 4194304
  u16* ctxg = ws + 20971520;        // 4194304
  float* dsc = (float*)(ws + 25165824);  // 4096 floats

  cast_all<<<8192, 256, 0, stream>>>(hs, Wq, Wk, Wv, Wo, delta, ws, dsc);

  gemm_qkv256<<<dim3(12, 16), 512, 0, stream>>>(hsb, wqkv, bq, bk, bv, tau, qg, kg, vTg);
  attn<<<256, 512, 0, stream>>>(qg, kg, vTg, dsc, ctxg);
  gemm_out<<<dim3(8, 32), 256, 0, stream>>>(ctxg, wob, bo, out);
}

// Round 10
// 147.111 us; speedup vs baseline: 1.4517x; 1.0224x over previous
//
#include <hip/hip_runtime.h>

#define B_ 2
#define L_ 2048
#define H_ 1024
#define NH_ 16
#define HD_ 64

using short8 = __attribute__((__ext_vector_type__(8))) short;
using f32x4 = __attribute__((__ext_vector_type__(4))) float;
using f32x16 = __attribute__((__ext_vector_type__(16))) float;
typedef unsigned short u16;
typedef unsigned int u32;

__device__ __forceinline__ u16 f2bf(float f) {
  union { float f; unsigned u; } x{f};
  unsigned u = x.u;
  u = u + 0x7FFFu + ((u >> 16) & 1u);  // round-to-nearest-even
  return (u16)(u >> 16);
}

__device__ __forceinline__ void gld16(const void* g, void* l) {
  __builtin_amdgcn_global_load_lds(
      (const __attribute__((address_space(1))) void*)g,
      (__attribute__((address_space(3))) void*)l, 16, 0, 0);
}

#define MFMA16(a, b, c) __builtin_amdgcn_mfma_f32_16x16x32_bf16((a), (b), (c), 0, 0, 0)
#define MFMA32(a, b, c) __builtin_amdgcn_mfma_f32_32x32x16_bf16((a), (b), (c), 0, 0, 0)

// ---------------- fused cast: hs|Wq|Wk|Wv|Wo -> bf16 (contiguous dst), delta prescale ----------------
__global__ void cast_all(const float* __restrict__ hs, const float* __restrict__ Wq,
                         const float* __restrict__ Wk, const float* __restrict__ Wv,
                         const float* __restrict__ Wo, const float* __restrict__ delta,
                         u16* __restrict__ dst, float* __restrict__ dsc) {
  const int t = blockIdx.x * 256 + threadIdx.x;
  const int i = t * 4;
  const float* src;
  int off;
  if (i < 4194304) {
    src = hs; off = i;
  } else {
    const int j = i - 4194304;
    const int w = j >> 20;
    off = j & 1048575;
    src = (w == 0) ? Wq : (w == 1) ? Wk : (w == 2) ? Wv : Wo;
  }
  float4 v = *(const float4*)(src + off);
  *(ushort4*)(dst + i) = make_ushort4(f2bf(v.x), f2bf(v.y), f2bf(v.z), f2bf(v.w));
  if (t < 4096) dsc[t] = delta[t] * 0.18033688011112042f;  // 0.125*log2(e)
}

// ---------------- QKV GEMM, 256x256 tile, counted-vmcnt pipeline ----------------
__global__ __launch_bounds__(512) void gemm_qkv256(
    const u16* __restrict__ A, const u16* __restrict__ W,
    const float* __restrict__ bq, const float* __restrict__ bk, const float* __restrict__ bv,
    const float* __restrict__ tau,
    u16* __restrict__ qg, u16* __restrict__ kg, u16* __restrict__ vTg) {
  __shared__ u16 As[2][256 * 64];
  __shared__ u16 Bs[2][256 * 64];
  const int tid = threadIdx.x;
  const int lane = tid & 63;
  const int wid = tid >> 6;
  const int wr = wid >> 2;   // 0..1 -> rows wr*128..+128
  const int wc = wid & 3;    // 0..3 -> cols wc*64..+64
  // bijective XCD swizzle: 192 blocks -> 24 consecutive per XCD (W-panel locality)
  const int orig = blockIdx.y * 12 + blockIdx.x;
  const int wg = (orig & 7) * 24 + (orig >> 3);
  const int m0 = (wg & 15) * 256;
  const int n0 = (wg >> 4) * 256;

  const int srow = tid >> 3;          // 0..63 within each li group
  const int sg = tid & 7;             // dest granule

#define STAGE256(slot, t_)                                                              \
  {                                                                                     \
    const int kt64 = (t_) * 64;                                                         \
    _Pragma("unroll") for (int li = 0; li < 4; li++) {                                  \
      const int row = li * 64 + srow;                                                   \
      const int gsrc = sg ^ (row & 7);                                                  \
      gld16(A + (size_t)(m0 + row) * 1024 + kt64 + gsrc * 8,                            \
            (char*)As[slot] + li * 8192 + wid * 1024 + lane * 16);                      \
      gld16(W + (size_t)(n0 + row) * 1024 + kt64 + gsrc * 8,                            \
            (char*)Bs[slot] + li * 8192 + wid * 1024 + lane * 16);                      \
    }                                                                                   \
  }

  f32x4 acc[8][4] = {};

  STAGE256(0, 0);
  STAGE256(1, 1);

  for (int t = 0; t < 16; t++) {
    if (t >= 1 && t + 1 < 16) STAGE256((t + 1) & 1, t + 1);
    if (t + 1 < 16) {
      asm volatile("s_waitcnt vmcnt(8)" ::: "memory");
    } else {
      asm volatile("s_waitcnt vmcnt(0)" ::: "memory");
    }
    asm volatile("s_barrier" ::: "memory");
    const u16* Ab = As[t & 1];
    const u16* Bb = Bs[t & 1];
    short8 bf[4];
#pragma unroll
    for (int q = 0; q < 4; q++) {
      const int mh = q & 1, ks = q >> 1;
      const int g0 = ks * 4 + (lane >> 4);
      if (mh == 0) {
#pragma unroll
        for (int ni = 0; ni < 4; ni++) {
          const int r = wc * 64 + ni * 16 + (lane & 15);
          bf[ni] = *(const short8*)((const char*)Bb + r * 128 + ((g0 ^ (r & 7)) << 4));
        }
      }
      short8 af[4];
#pragma unroll
      for (int mi = 0; mi < 4; mi++) {
        const int r = wr * 128 + (mh * 4 + mi) * 16 + (lane & 15);
        af[mi] = *(const short8*)((const char*)Ab + r * 128 + ((g0 ^ (r & 7)) << 4));
      }
      __builtin_amdgcn_s_setprio(1);
#pragma unroll
      for (int mi = 0; mi < 4; mi++)
#pragma unroll
        for (int ni = 0; ni < 4; ni++)
          acc[mh * 4 + mi][ni] = MFMA16(af[mi], bf[ni], acc[mh * 4 + mi][ni]);
      __builtin_amdgcn_s_setprio(0);
      asm volatile("s_barrier" ::: "memory");
    }
  }

  const int which = n0 >> 10;  // 0=q 1=k 2=v, uniform per block (1024/256=4 blocks each)
  const int b_blk = m0 >> 11;
  const float scl = (which == 0) ? tau[b_blk] * 0.18033688011112042f : 1.0f;
  const float* bias = which == 0 ? bq : (which == 1 ? bk : bv);
#pragma unroll
  for (int ni = 0; ni < 4; ni++) {
    const int n = n0 + wc * 64 + ni * 16 + (lane & 15);
    const int nn = n & 1023;
    const int h = nn >> 6, d = nn & 63;
    const float bb = bias[nn];
#pragma unroll
    for (int mi = 0; mi < 8; mi++) {
      const int mb = m0 + wr * 128 + mi * 16 + ((lane >> 4) << 2);
      const int b = mb >> 11;
      const int lq = mb & 2047;
      if (which == 2) {
        ushort4 pk = make_ushort4(f2bf(acc[mi][ni][0] + bb), f2bf(acc[mi][ni][1] + bb),
                                  f2bf(acc[mi][ni][2] + bb), f2bf(acc[mi][ni][3] + bb));
        *(ushort4*)&vTg[((size_t)(b * NH_ + h) * HD_ + d) * L_ + lq] = pk;
      } else {
        u16* dst = which == 0 ? qg : kg;
#pragma unroll
        for (int r = 0; r < 4; r++)
          dst[((size_t)(b * NH_ + h) * L_ + lq + r) * HD_ + d] = f2bf((acc[mi][ni][r] + bb) * scl);
      }
    }
  }
}

// ---------------- flash attention, 8-wave blocks, 3-buffer ring + QK prefetch pipeline ----------------
// grid 256 XCD-swizzled; 512 threads (8 waves x 32 q-rows). Per iter t:
// STAGE(t+2) || QK(t+1) [MFMA] || softmax(t) [VALU] -> PV(t) [MFMA] -> barrier.
__global__ __launch_bounds__(512) void attn(
    const u16* __restrict__ qg, const u16* __restrict__ kg, const u16* __restrict__ vTg,
    const float* __restrict__ dsc, u16* __restrict__ ctxg) {
  // 3 buffers x 16KB: 8 K blocks (2 kt x 4 ks) + 8 V blocks (2 kt x 2 dt x 2 ks2), 1KB each
  __shared__ u16 lds[3][8192];
  const int tid = threadIdx.x;
  const int lane = tid & 63;
  const int wv = tid >> 6;   // 0..7
  const int lane31 = lane & 31;
  const int hi = lane >> 5;
  // bijective XCD-chunk swizzle: nwg=256 -> 32 consecutive wgids (4 bh) per XCD
  const int orig = blockIdx.x;
  const int wgid = (orig & 7) * 32 + (orig >> 3);
  const int bh = wgid >> 3;
  const int qblk = wgid & 7;
  const int b = bh >> 4;
  const int h = bh & 15;
  const int q0 = qblk * 256 + wv * 32;
  const u16* qb = qg + (size_t)bh * L_ * HD_;
  const u16* kb = kg + (size_t)bh * L_ * HD_;
  const u16* vb = vTg + (size_t)bh * HD_ * L_;
  const float* db = dsc + (size_t)b * L_;

  // Q fragments (B-operand): lane holds Q[q0+lane31][ks*16 + hi*8 .. +7]
  short8 qf[4];
#pragma unroll
  for (int ks = 0; ks < 4; ks++)
    qf[ks] = *(const short8*)&qb[(size_t)(q0 + lane31) * 64 + ks * 16 + hi * 8];

  // ones A-fragment: row d=0 all-ones -> l accumulates in acc_l row 0
  union { u32 u[4]; short8 s; } onesu;
  const u32 ow = (lane31 == 0) ? 0x3F803F80u : 0u;
  onesu.u[0] = ow; onesu.u[1] = ow; onesu.u[2] = ow; onesu.u[3] = ow;
  const short8 onesf = onesu.s;

  f32x16 acc[2] = {};   // ctx^T: [dtile] rows d=crow(r,hi), col q=lane31
  f32x16 accl = {};     // row 0 = running softmax denominator per q
  float mrun = -__builtin_inff();

  // staging: wave wv stages K block wv and V block wv (1 KB each) of one 64-key tile
#define STAGE(bp_, j0)                                                                    \
  {                                                                                       \
    u16* bp = (bp_);                                                                      \
    {                                                                                     \
      const int kt = wv >> 2, ks = wv & 3;                                                \
      gld16(kb + (size_t)((j0) + kt * 32 + lane31) * 64 + ks * 16 + hi * 8,               \
            bp + wv * 512 + lane * 8);                                                    \
    }                                                                                     \
    {                                                                                     \
      const int kt = wv >> 2, dt = (wv >> 1) & 1, ks2 = wv & 1;                           \
      gld16(vb + (size_t)(dt * 32 + lane31) * L_ + (j0) + kt * 32 + ks2 * 16 + hi * 8,    \
            bp + (8 + wv) * 512 + lane * 8);                                              \
    }                                                                                     \
  }

// QK^T for one 64-key tile from buffer bp_ into sA_/sB_ (two independent chains)
#define QK64(bp_, sA_, sB_)                                                               \
  {                                                                                       \
    const u16* bp = (bp_);                                                                \
    __builtin_amdgcn_s_setprio(1);                                                        \
    _Pragma("unroll") for (int ks = 0; ks < 4; ks++) {                                    \
      short8 kf0 = *(const short8*)&bp[(0 * 4 + ks) * 512 + lane * 8];                    \
      short8 kf1 = *(const short8*)&bp[(1 * 4 + ks) * 512 + lane * 8];                    \
      sA_ = MFMA32(kf0, qf[ks], sA_);                                                     \
      sB_ = MFMA32(kf1, qf[ks], sB_);                                                     \
    }                                                                                     \
    __builtin_amdgcn_s_setprio(0);                                                        \
  }

  STAGE(lds[0], 0);
  STAGE(lds[1], 64);
  __syncthreads();

  f32x16 sp0 = {}, sp1 = {};
  QK64(lds[0], sp0, sp1);

  int cur = 0, nxt = 1, fut = 2;
  for (int t = 0; t < 32; t++) {
    const int j0 = t * 64;
    if (t + 2 < 32) STAGE(lds[fut], j0 + 128);
    // QK prefetch for tile t+1 (independent of softmax below -> MFMA/VALU overlap)
    f32x16 sn0 = {}, sn1 = {};
    if (t + 1 < 32) QK64(lds[nxt], sn0, sn1);

    // ---- softmax on tile t (sp0=keys j0.., sp1=keys j0+32..), joint over 64 keys ----
#pragma unroll
    for (int g = 0; g < 4; g++) {
      float4 dl0 = *(const float4*)&db[j0 + g * 8 + hi * 4];
      float4 dl1 = *(const float4*)&db[j0 + 32 + g * 8 + hi * 4];
      sp0[g * 4 + 0] += dl0.x; sp0[g * 4 + 1] += dl0.y;
      sp0[g * 4 + 2] += dl0.z; sp0[g * 4 + 3] += dl0.w;
      sp1[g * 4 + 0] += dl1.x; sp1[g * 4 + 1] += dl1.y;
      sp1[g * 4 + 2] += dl1.z; sp1[g * 4 + 3] += dl1.w;
    }
    float tm[8];
#pragma unroll
    for (int r = 0; r < 8; r++) tm[r] = fmaxf(fmaxf(sp0[r], sp0[8 + r]), fmaxf(sp1[r], sp1[8 + r]));
#pragma unroll
    for (int r = 0; r < 4; r++) tm[r] = fmaxf(tm[r], tm[4 + r]);
    float pmax = fmaxf(fmaxf(tm[0], tm[1]), fmaxf(tm[2], tm[3]));
    pmax = fmaxf(pmax, __shfl_xor(pmax, 32));
    if (!__all(pmax - mrun <= 11.5f)) {
      float mnew = fmaxf(mrun, pmax);
      float al = __builtin_amdgcn_exp2f(mrun - mnew);
      mrun = mnew;
      accl[0] *= al;
#pragma unroll
      for (int dt = 0; dt < 2; dt++)
#pragma unroll
        for (int r = 0; r < 16; r++) acc[dt][r] *= al;
    }
#pragma unroll
    for (int r = 0; r < 16; r++) {
      sp0[r] = __builtin_amdgcn_exp2f(sp0[r] - mrun);
      sp1[r] = __builtin_amdgcn_exp2f(sp1[r] - mrun);
    }
    // pack both kt tiles to bf16 PV fragments in-register
    u32 pk[16];
#pragma unroll
    for (int i = 0; i < 8; i++) {
      asm("v_cvt_pk_bf16_f32 %0, %1, %2" : "=v"(pk[i]) : "v"(sp0[2 * i]), "v"(sp0[2 * i + 1]));
      asm("v_cvt_pk_bf16_f32 %0, %1, %2" : "=v"(pk[8 + i]) : "v"(sp1[2 * i]), "v"(sp1[2 * i + 1]));
    }
#pragma unroll
    for (int kt = 0; kt < 2; kt++) {
      asm volatile("v_permlane32_swap_b32 %0, %1" : "+v"(pk[kt * 8 + 0]), "+v"(pk[kt * 8 + 2]));
      asm volatile("v_permlane32_swap_b32 %0, %1" : "+v"(pk[kt * 8 + 1]), "+v"(pk[kt * 8 + 3]));
      asm volatile("v_permlane32_swap_b32 %0, %1" : "+v"(pk[kt * 8 + 4]), "+v"(pk[kt * 8 + 6]));
      asm volatile("v_permlane32_swap_b32 %0, %1" : "+v"(pk[kt * 8 + 5]), "+v"(pk[kt * 8 + 7]));
    }
    // ---- PV(t): ctx^T += V^T . P ; accl += ones . P ----
    {
      const u16* bp = lds[cur];
      __builtin_amdgcn_s_setprio(1);
#pragma unroll
      for (int kt = 0; kt < 2; kt++)
#pragma unroll
        for (int ks2 = 0; ks2 < 2; ks2++) {
          union U8 { u32 u[4]; short8 s; } pf;
          pf.u[0] = pk[kt * 8 + ks2 * 4 + 0];
          pf.u[1] = pk[kt * 8 + ks2 * 4 + 1];
          pf.u[2] = pk[kt * 8 + ks2 * 4 + 2];
          pf.u[3] = pk[kt * 8 + ks2 * 4 + 3];
#pragma unroll
          for (int dt = 0; dt < 2; dt++) {
            short8 vf = *(const short8*)&bp[(8 + kt * 4 + dt * 2 + ks2) * 512 + lane * 8];
            acc[dt] = MFMA32(vf, pf.s, acc[dt]);
          }
          accl = MFMA32(onesf, pf.s, accl);
        }
      __builtin_amdgcn_s_setprio(0);
    }
    __syncthreads();
    sp0 = sn0; sp1 = sn1;
    const int tmp = cur; cur = nxt; nxt = fut; fut = tmp;
  }

  // epilogue: transpose ctx^T -> ctx via swizzled per-wave LDS tile, coalesced store
  u16* tw = (u16*)lds + wv * 2048;  // 4KB per wave: [32 q][64 d] bf16, XOR-swizzled
  const float l0 = accl[0];
  const float l1 = __shfl_xor(l0, 32);
  const float inv = 1.0f / (hi ? l1 : l0);
#pragma unroll
  for (int dt = 0; dt < 2; dt++)
#pragma unroll
    for (int g = 0; g < 4; g++) {
      ushort4 w4 = make_ushort4(f2bf(acc[dt][g * 4 + 0] * inv), f2bf(acc[dt][g * 4 + 1] * inv),
                                f2bf(acc[dt][g * 4 + 2] * inv), f2bf(acc[dt][g * 4 + 3] * inv));
      const int d0 = dt * 32 + g * 8 + hi * 4;
      const int byte = (lane31 * 128 + d0 * 2) ^ ((lane31 & 15) << 3);
      *(ushort4*)((char*)tw + byte) = w4;
    }
  asm volatile("s_waitcnt lgkmcnt(0)" ::: "memory");
  const size_t obase = ((size_t)b * L_ + q0) * 1024 + h * 64;
#pragma unroll
  for (int i = 0; i < 16; i++) {
    const int qr = 2 * i + hi;
    const int byte = (qr * 128 + lane31 * 4) ^ ((qr & 15) << 3);
    const u32 val = *(const u32*)((const char*)tw + byte);
    *(u32*)&ctxg[obase + (size_t)qr * 1024 + lane31 * 2] = val;
  }
}

// ---------------- output GEMM: ctx[4096,1024] x Wo[1024,1024]^T + bo -> f32 ----------------
__global__ __launch_bounds__(256) void gemm_out(
    const u16* __restrict__ A, const u16* __restrict__ W,
    const float* __restrict__ bo, float* __restrict__ out) {
  __shared__ u16 As[128 * 64];
  __shared__ u16 Bs[128 * 64];
  const int tid = threadIdx.x;
  const int lane = tid & 63;
  const int wave = tid >> 6;
  const int wrow = (wave >> 1) * 64;
  const int wcol = (wave & 1) * 64;
  const int m0 = blockIdx.y * 128;
  const int n0 = blockIdx.x * 128;
  const int rr = tid >> 3;
  const int c8 = (tid & 7) * 8;
  f32x4 acc[4][4] = {};
  for (int kt = 0; kt < 1024; kt += 64) {
#pragma unroll
    for (int i = 0; i < 4; i++) {
      gld16(A + (size_t)(m0 + i * 32 + rr) * 1024 + kt + c8, (char*)As + i * 4096 + wave * 1024);
      gld16(W + (size_t)(n0 + i * 32 + rr) * 1024 + kt + c8, (char*)Bs + i * 4096 + wave * 1024);
    }
    __syncthreads();
#pragma unroll
    for (int kc = 0; kc < 2; kc++) {
      const int ko = kc * 32 + (lane >> 4) * 8;
      short8 af[4], bf[4];
#pragma unroll
      for (int mi = 0; mi < 4; mi++)
        af[mi] = *(const short8*)&As[(wrow + mi * 16 + (lane & 15)) * 64 + ko];
#pragma unroll
      for (int ni = 0; ni < 4; ni++)
        bf[ni] = *(const short8*)&Bs[(wcol + ni * 16 + (lane & 15)) * 64 + ko];
#pragma unroll
      for (int mi = 0; mi < 4; mi++)
#pragma unroll
        for (int ni = 0; ni < 4; ni++)
          acc[mi][ni] = MFMA16(af[mi], bf[ni], acc[mi][ni]);
    }
    __syncthreads();
  }
#pragma unroll
  for (int ni = 0; ni < 4; ni++) {
    const int n = n0 + wcol + ni * 16 + (lane & 15);
    const float bb = bo[n];
#pragma unroll
    for (int mi = 0; mi < 4; mi++) {
      const int mb = m0 + wrow + mi * 16 + ((lane >> 4) << 2);
#pragma unroll
      for (int r = 0; r < 4; r++)
        out[(size_t)(mb + r) * 1024 + n] = acc[mi][ni][r] + bb;
    }
  }
}

extern "C" void kernel_launch(void* const* d_in, const int* in_sizes, int n_in,
                              void* d_out, int out_size, void* d_ws, size_t ws_size,
                              hipStream_t stream) {
  const float* hs = (const float*)d_in[0];
  const float* tau = (const float*)d_in[1];
  const float* delta = (const float*)d_in[2];
  const float* Wq = (const float*)d_in[3];
  const float* bq = (const float*)d_in[4];
  const float* Wk = (const float*)d_in[5];
  const float* bk = (const float*)d_in[6];
  const float* Wv = (const float*)d_in[7];
  const float* bv = (const float*)d_in[8];
  const float* Wo = (const float*)d_in[9];
  const float* bo = (const float*)d_in[10];
  float* out = (float*)d_out;

  u16* ws = (u16*)d_ws;
  u16* hsb  = ws;                   // 4194304
  u16* wqkv = ws + 4194304;         // 3145728 (Wq|Wk|Wv)
  u16* wob  = ws + 7340032;         // 1048576
  u16* qg   = ws + 8388608;         // 4194304
  u16* kg   = ws + 12582912;        // 4194304
  u16* vTg  = ws + 16777216;        // 4194304
  u16* ctxg = ws + 20971520;        // 4194304
  float* dsc = (float*)(ws + 25165824);  // 4096 floats

  cast_all<<<8192, 256, 0, stream>>>(hs, Wq, Wk, Wv, Wo, delta, ws, dsc);

  gemm_qkv256<<<dim3(12, 16), 512, 0, stream>>>(hsb, wqkv, bq, bk, bv, tau, qg, kg, vTg);
  attn<<<256, 512, 0, stream>>>(qg, kg, vTg, dsc, ctxg);
  gemm_out<<<dim3(8, 32), 256, 0, stream>>>(ctxg, wob, bo, out);
}

// Round 11
// 139.161 us; speedup vs baseline: 1.5346x; 1.0571x over previous
//
#include <hip/hip_runtime.h>

#define B_ 2
#define L_ 2048
#define H_ 1024
#define NH_ 16
#define HD_ 64

using short8 = __attribute__((__ext_vector_type__(8))) short;
using f32x4 = __attribute__((__ext_vector_type__(4))) float;
using f32x16 = __attribute__((__ext_vector_type__(16))) float;
typedef unsigned short u16;
typedef unsigned int u32;

__device__ __forceinline__ u16 f2bf(float f) {
  union { float f; unsigned u; } x{f};
  unsigned u = x.u;
  u = u + 0x7FFFu + ((u >> 16) & 1u);  // round-to-nearest-even
  return (u16)(u >> 16);
}

__device__ __forceinline__ void gld16(const void* g, void* l) {
  __builtin_amdgcn_global_load_lds(
      (const __attribute__((address_space(1))) void*)g,
      (__attribute__((address_space(3))) void*)l, 16, 0, 0);
}

#define MFMA16(a, b, c) __builtin_amdgcn_mfma_f32_16x16x32_bf16((a), (b), (c), 0, 0, 0)
#define MFMA32(a, b, c) __builtin_amdgcn_mfma_f32_32x32x16_bf16((a), (b), (c), 0, 0, 0)

// ---------------- fused cast: hs|Wq|Wk|Wv|Wo -> bf16 (contiguous dst), delta prescale ----------------
__global__ void cast_all(const float* __restrict__ hs, const float* __restrict__ Wq,
                         const float* __restrict__ Wk, const float* __restrict__ Wv,
                         const float* __restrict__ Wo, const float* __restrict__ delta,
                         u16* __restrict__ dst, float* __restrict__ dsc) {
  const int t = blockIdx.x * 256 + threadIdx.x;
  const int i = t * 4;
  const float* src;
  int off;
  if (i < 4194304) {
    src = hs; off = i;
  } else {
    const int j = i - 4194304;
    const int w = j >> 20;
    off = j & 1048575;
    src = (w == 0) ? Wq : (w == 1) ? Wk : (w == 2) ? Wv : Wo;
  }
  float4 v = *(const float4*)(src + off);
  *(ushort4*)(dst + i) = make_ushort4(f2bf(v.x), f2bf(v.y), f2bf(v.z), f2bf(v.w));
  if (t < 4096) dsc[t] = delta[t] * 0.18033688011112042f;  // 0.125*log2(e)
}

// ---------------- QKV GEMM, 256x192 tile, counted-vmcnt pipeline, 256 blocks (full CU coverage) ----------------
__global__ __launch_bounds__(512) void gemm_qkv192(
    const u16* __restrict__ A, const u16* __restrict__ W,
    const float* __restrict__ bq, const float* __restrict__ bk, const float* __restrict__ bv,
    const float* __restrict__ tau,
    u16* __restrict__ qg, u16* __restrict__ kg, u16* __restrict__ vTg) {
  __shared__ u16 As[2][256 * 64];   // 64 KB
  __shared__ u16 Bs[2][192 * 64];   // 48 KB
  const int tid = threadIdx.x;
  const int lane = tid & 63;
  const int wid = tid >> 6;
  const int wr = wid >> 2;   // 0..1 -> rows wr*128..+128
  const int wc = wid & 3;    // 0..3 -> cols wc*48..+48
  // bijective XCD swizzle: 256 blocks -> 32 consecutive per XCD
  const int orig = blockIdx.y * 16 + blockIdx.x;
  const int wg = (orig & 7) * 32 + (orig >> 3);
  const int m0 = (wg & 15) * 256;
  const int n0 = (wg >> 4) * 192;

  const int srow = tid >> 3;          // 0..63
  const int sg = tid & 7;             // granule

#define STAGEQ(slot, t_)                                                                \
  {                                                                                     \
    const int kt64 = (t_) * 64;                                                         \
    _Pragma("unroll") for (int li = 0; li < 4; li++) {                                  \
      const int row = li * 64 + srow;                                                   \
      const int gsrc = sg ^ (row & 7);                                                  \
      gld16(A + (size_t)(m0 + row) * 1024 + kt64 + gsrc * 8,                            \
            (char*)As[slot] + li * 8192 + wid * 1024 + lane * 16);                      \
    }                                                                                   \
    _Pragma("unroll") for (int li = 0; li < 3; li++) {                                  \
      const int row = li * 64 + srow;                                                   \
      const int gsrc = sg ^ (row & 7);                                                  \
      gld16(W + (size_t)(n0 + row) * 1024 + kt64 + gsrc * 8,                            \
            (char*)Bs[slot] + li * 8192 + wid * 1024 + lane * 16);                      \
    }                                                                                   \
  }

  f32x4 acc[8][3] = {};

  STAGEQ(0, 0);
  STAGEQ(1, 1);

  for (int t = 0; t < 16; t++) {
    if (t >= 1 && t + 1 < 16) STAGEQ((t + 1) & 1, t + 1);
    if (t + 1 < 16) {
      asm volatile("s_waitcnt vmcnt(7)" ::: "memory");
    } else {
      asm volatile("s_waitcnt vmcnt(0)" ::: "memory");
    }
    asm volatile("s_barrier" ::: "memory");
    const u16* Ab = As[t & 1];
    const u16* Bb = Bs[t & 1];
    short8 bf[3];
#pragma unroll
    for (int q = 0; q < 4; q++) {
      const int mh = q & 1, ks = q >> 1;
      const int g0 = ks * 4 + (lane >> 4);
      if (mh == 0) {
#pragma unroll
        for (int ni = 0; ni < 3; ni++) {
          const int r = wc * 48 + ni * 16 + (lane & 15);
          bf[ni] = *(const short8*)((const char*)Bb + r * 128 + ((g0 ^ (r & 7)) << 4));
        }
      }
      short8 af[4];
#pragma unroll
      for (int mi = 0; mi < 4; mi++) {
        const int r = wr * 128 + (mh * 4 + mi) * 16 + (lane & 15);
        af[mi] = *(const short8*)((const char*)Ab + r * 128 + ((g0 ^ (r & 7)) << 4));
      }
      __builtin_amdgcn_s_setprio(1);
#pragma unroll
      for (int mi = 0; mi < 4; mi++)
#pragma unroll
        for (int ni = 0; ni < 3; ni++)
          acc[mh * 4 + mi][ni] = MFMA16(af[mi], bf[ni], acc[mh * 4 + mi][ni]);
      __builtin_amdgcn_s_setprio(0);
      asm volatile("s_barrier" ::: "memory");
    }
  }

  const int b_blk = m0 >> 11;
  const float tauv = tau[b_blk] * 0.18033688011112042f;
#pragma unroll
  for (int ni = 0; ni < 3; ni++) {
    const int nbase = n0 + wc * 48 + ni * 16;          // 16-aligned -> never straddles q/k/v boundary
    const int which = nbase >> 10;                     // 0=q 1=k 2=v, uniform per ni-group
    const int n = nbase + (lane & 15);
    const int nn = n & 1023;
    const int h = nn >> 6, d = nn & 63;
    const float* bias = which == 0 ? bq : (which == 1 ? bk : bv);
    const float bb = bias[nn];
    const float scl = which == 0 ? tauv : 1.0f;
#pragma unroll
    for (int mi = 0; mi < 8; mi++) {
      const int mb = m0 + wr * 128 + mi * 16 + ((lane >> 4) << 2);
      const int b = mb >> 11;
      const int lq = mb & 2047;
      if (which == 2) {
        ushort4 pk = make_ushort4(f2bf(acc[mi][ni][0] + bb), f2bf(acc[mi][ni][1] + bb),
                                  f2bf(acc[mi][ni][2] + bb), f2bf(acc[mi][ni][3] + bb));
        *(ushort4*)&vTg[((size_t)(b * NH_ + h) * HD_ + d) * L_ + lq] = pk;
      } else {
        u16* dst = which == 0 ? qg : kg;
#pragma unroll
        for (int r = 0; r < 4; r++)
          dst[((size_t)(b * NH_ + h) * L_ + lq + r) * HD_ + d] = f2bf((acc[mi][ni][r] + bb) * scl);
      }
    }
  }
}

// ---------------- flash attention, 8-wave blocks, 3-buffer ring + QK prefetch pipeline (R10) ----------------
__global__ __launch_bounds__(512) void attn(
    const u16* __restrict__ qg, const u16* __restrict__ kg, const u16* __restrict__ vTg,
    const float* __restrict__ dsc, u16* __restrict__ ctxg) {
  __shared__ u16 lds[3][8192];
  const int tid = threadIdx.x;
  const int lane = tid & 63;
  const int wv = tid >> 6;   // 0..7
  const int lane31 = lane & 31;
  const int hi = lane >> 5;
  const int orig = blockIdx.x;
  const int wgid = (orig & 7) * 32 + (orig >> 3);
  const int bh = wgid >> 3;
  const int qblk = wgid & 7;
  const int b = bh >> 4;
  const int h = bh & 15;
  const int q0 = qblk * 256 + wv * 32;
  const u16* qb = qg + (size_t)bh * L_ * HD_;
  const u16* kb = kg + (size_t)bh * L_ * HD_;
  const u16* vb = vTg + (size_t)bh * HD_ * L_;
  const float* db = dsc + (size_t)b * L_;

  short8 qf[4];
#pragma unroll
  for (int ks = 0; ks < 4; ks++)
    qf[ks] = *(const short8*)&qb[(size_t)(q0 + lane31) * 64 + ks * 16 + hi * 8];

  union { u32 u[4]; short8 s; } onesu;
  const u32 ow = (lane31 == 0) ? 0x3F803F80u : 0u;
  onesu.u[0] = ow; onesu.u[1] = ow; onesu.u[2] = ow; onesu.u[3] = ow;
  const short8 onesf = onesu.s;

  f32x16 acc[2] = {};
  f32x16 accl = {};
  float mrun = -__builtin_inff();

#define STAGE(bp_, j0)                                                                    \
  {                                                                                       \
    u16* bp = (bp_);                                                                      \
    {                                                                                     \
      const int kt = wv >> 2, ks = wv & 3;                                                \
      gld16(kb + (size_t)((j0) + kt * 32 + lane31) * 64 + ks * 16 + hi * 8,               \
            bp + wv * 512 + lane * 8);                                                    \
    }                                                                                     \
    {                                                                                     \
      const int kt = wv >> 2, dt = (wv >> 1) & 1, ks2 = wv & 1;                           \
      gld16(vb + (size_t)(dt * 32 + lane31) * L_ + (j0) + kt * 32 + ks2 * 16 + hi * 8,    \
            bp + (8 + wv) * 512 + lane * 8);                                              \
    }                                                                                     \
  }

#define QK64(bp_, sA_, sB_)                                                               \
  {                                                                                       \
    const u16* bp = (bp_);                                                                \
    __builtin_amdgcn_s_setprio(1);                                                        \
    _Pragma("unroll") for (int ks = 0; ks < 4; ks++) {                                    \
      short8 kf0 = *(const short8*)&bp[(0 * 4 + ks) * 512 + lane * 8];                    \
      short8 kf1 = *(const short8*)&bp[(1 * 4 + ks) * 512 + lane * 8];                    \
      sA_ = MFMA32(kf0, qf[ks], sA_);                                                     \
      sB_ = MFMA32(kf1, qf[ks], sB_);                                                     \
    }                                                                                     \
    __builtin_amdgcn_s_setprio(0);                                                        \
  }

  STAGE(lds[0], 0);
  STAGE(lds[1], 64);
  __syncthreads();

  f32x16 sp0 = {}, sp1 = {};
  QK64(lds[0], sp0, sp1);

  int cur = 0, nxt = 1, fut = 2;
  for (int t = 0; t < 32; t++) {
    const int j0 = t * 64;
    if (t + 2 < 32) STAGE(lds[fut], j0 + 128);
    f32x16 sn0 = {}, sn1 = {};
    if (t + 1 < 32) QK64(lds[nxt], sn0, sn1);

#pragma unroll
    for (int g = 0; g < 4; g++) {
      float4 dl0 = *(const float4*)&db[j0 + g * 8 + hi * 4];
      float4 dl1 = *(const float4*)&db[j0 + 32 + g * 8 + hi * 4];
      sp0[g * 4 + 0] += dl0.x; sp0[g * 4 + 1] += dl0.y;
      sp0[g * 4 + 2] += dl0.z; sp0[g * 4 + 3] += dl0.w;
      sp1[g * 4 + 0] += dl1.x; sp1[g * 4 + 1] += dl1.y;
      sp1[g * 4 + 2] += dl1.z; sp1[g * 4 + 3] += dl1.w;
    }
    float tm[8];
#pragma unroll
    for (int r = 0; r < 8; r++) tm[r] = fmaxf(fmaxf(sp0[r], sp0[8 + r]), fmaxf(sp1[r], sp1[8 + r]));
#pragma unroll
    for (int r = 0; r < 4; r++) tm[r] = fmaxf(tm[r], tm[4 + r]);
    float pmax = fmaxf(fmaxf(tm[0], tm[1]), fmaxf(tm[2], tm[3]));
    pmax = fmaxf(pmax, __shfl_xor(pmax, 32));
    if (!__all(pmax - mrun <= 11.5f)) {
      float mnew = fmaxf(mrun, pmax);
      float al = __builtin_amdgcn_exp2f(mrun - mnew);
      mrun = mnew;
      accl[0] *= al;
#pragma unroll
      for (int dt = 0; dt < 2; dt++)
#pragma unroll
        for (int r = 0; r < 16; r++) acc[dt][r] *= al;
    }
#pragma unroll
    for (int r = 0; r < 16; r++) {
      sp0[r] = __builtin_amdgcn_exp2f(sp0[r] - mrun);
      sp1[r] = __builtin_amdgcn_exp2f(sp1[r] - mrun);
    }
    u32 pk[16];
#pragma unroll
    for (int i = 0; i < 8; i++) {
      asm("v_cvt_pk_bf16_f32 %0, %1, %2" : "=v"(pk[i]) : "v"(sp0[2 * i]), "v"(sp0[2 * i + 1]));
      asm("v_cvt_pk_bf16_f32 %0, %1, %2" : "=v"(pk[8 + i]) : "v"(sp1[2 * i]), "v"(sp1[2 * i + 1]));
    }
#pragma unroll
    for (int kt = 0; kt < 2; kt++) {
      asm volatile("v_permlane32_swap_b32 %0, %1" : "+v"(pk[kt * 8 + 0]), "+v"(pk[kt * 8 + 2]));
      asm volatile("v_permlane32_swap_b32 %0, %1" : "+v"(pk[kt * 8 + 1]), "+v"(pk[kt * 8 + 3]));
      asm volatile("v_permlane32_swap_b32 %0, %1" : "+v"(pk[kt * 8 + 4]), "+v"(pk[kt * 8 + 6]));
      asm volatile("v_permlane32_swap_b32 %0, %1" : "+v"(pk[kt * 8 + 5]), "+v"(pk[kt * 8 + 7]));
    }
    {
      const u16* bp = lds[cur];
      __builtin_amdgcn_s_setprio(1);
#pragma unroll
      for (int kt = 0; kt < 2; kt++)
#pragma unroll
        for (int ks2 = 0; ks2 < 2; ks2++) {
          union U8 { u32 u[4]; short8 s; } pf;
          pf.u[0] = pk[kt * 8 + ks2 * 4 + 0];
          pf.u[1] = pk[kt * 8 + ks2 * 4 + 1];
          pf.u[2] = pk[kt * 8 + ks2 * 4 + 2];
          pf.u[3] = pk[kt * 8 + ks2 * 4 + 3];
#pragma unroll
          for (int dt = 0; dt < 2; dt++) {
            short8 vf = *(const short8*)&bp[(8 + kt * 4 + dt * 2 + ks2) * 512 + lane * 8];
            acc[dt] = MFMA32(vf, pf.s, acc[dt]);
          }
          accl = MFMA32(onesf, pf.s, accl);
        }
      __builtin_amdgcn_s_setprio(0);
    }
    __syncthreads();
    sp0 = sn0; sp1 = sn1;
    const int tmp = cur; cur = nxt; nxt = fut; fut = tmp;
  }

  u16* tw = (u16*)lds + wv * 2048;
  const float l0 = accl[0];
  const float l1 = __shfl_xor(l0, 32);
  const float inv = 1.0f / (hi ? l1 : l0);
#pragma unroll
  for (int dt = 0; dt < 2; dt++)
#pragma unroll
    for (int g = 0; g < 4; g++) {
      ushort4 w4 = make_ushort4(f2bf(acc[dt][g * 4 + 0] * inv), f2bf(acc[dt][g * 4 + 1] * inv),
                                f2bf(acc[dt][g * 4 + 2] * inv), f2bf(acc[dt][g * 4 + 3] * inv));
      const int d0 = dt * 32 + g * 8 + hi * 4;
      const int byte = (lane31 * 128 + d0 * 2) ^ ((lane31 & 15) << 3);
      *(ushort4*)((char*)tw + byte) = w4;
    }
  asm volatile("s_waitcnt lgkmcnt(0)" ::: "memory");
  const size_t obase = ((size_t)b * L_ + q0) * 1024 + h * 64;
#pragma unroll
  for (int i = 0; i < 16; i++) {
    const int qr = 2 * i + hi;
    const int byte = (qr * 128 + lane31 * 4) ^ ((qr & 15) << 3);
    const u32 val = *(const u32*)((const char*)tw + byte);
    *(u32*)&ctxg[obase + (size_t)qr * 1024 + lane31 * 2] = val;
  }
}

// ---------------- output GEMM, 128x128 tile, counted-vmcnt pipeline ----------------
__global__ __launch_bounds__(256) void gemm_out128(
    const u16* __restrict__ A, const u16* __restrict__ W,
    const float* __restrict__ bo, float* __restrict__ out) {
  __shared__ u16 As[2][128 * 64];   // 32 KB
  __shared__ u16 Bs[2][128 * 64];   // 32 KB
  const int tid = threadIdx.x;
  const int lane = tid & 63;
  const int wid = tid >> 6;
  const int wr = wid >> 1;   // 0..1
  const int wc = wid & 1;    // 0..1
  const int orig = blockIdx.y * 8 + blockIdx.x;
  const int wg = (orig & 7) * 32 + (orig >> 3);
  const int m0 = (wg & 31) * 128;
  const int n0 = (wg >> 5) * 128;

  const int srow = tid >> 3;          // 0..31
  const int sg = tid & 7;

#define STAGEO(slot, t_)                                                                \
  {                                                                                     \
    const int kt64 = (t_) * 64;                                                         \
    _Pragma("unroll") for (int li = 0; li < 4; li++) {                                  \
      const int row = li * 32 + srow;                                                   \
      const int gsrc = sg ^ (row & 7);                                                  \
      gld16(A + (size_t)(m0 + row) * 1024 + kt64 + gsrc * 8,                            \
            (char*)As[slot] + li * 4096 + wid * 1024 + lane * 16);                      \
      gld16(W + (size_t)(n0 + row) * 1024 + kt64 + gsrc * 8,                            \
            (char*)Bs[slot] + li * 4096 + wid * 1024 + lane * 16);                      \
    }                                                                                   \
  }

  f32x4 acc[4][4] = {};

  STAGEO(0, 0);
  STAGEO(1, 1);

  for (int t = 0; t < 16; t++) {
    if (t >= 1 && t + 1 < 16) STAGEO((t + 1) & 1, t + 1);
    if (t + 1 < 16) {
      asm volatile("s_waitcnt vmcnt(8)" ::: "memory");
    } else {
      asm volatile("s_waitcnt vmcnt(0)" ::: "memory");
    }
    asm volatile("s_barrier" ::: "memory");
    const u16* Ab = As[t & 1];
    const u16* Bb = Bs[t & 1];
    short8 bf[4];
#pragma unroll
    for (int q = 0; q < 4; q++) {
      const int mh = q & 1, ks = q >> 1;
      const int g0 = ks * 4 + (lane >> 4);
      if (mh == 0) {
#pragma unroll
        for (int ni = 0; ni < 4; ni++) {
          const int r = wc * 64 + ni * 16 + (lane & 15);
          bf[ni] = *(const short8*)((const char*)Bb + r * 128 + ((g0 ^ (r & 7)) << 4));
        }
      }
      short8 af[2];
#pragma unroll
      for (int mi = 0; mi < 2; mi++) {
        const int r = wr * 64 + (mh * 2 + mi) * 16 + (lane & 15);
        af[mi] = *(const short8*)((const char*)Ab + r * 128 + ((g0 ^ (r & 7)) << 4));
      }
      __builtin_amdgcn_s_setprio(1);
#pragma unroll
      for (int mi = 0; mi < 2; mi++)
#pragma unroll
        for (int ni = 0; ni < 4; ni++)
          acc[mh * 2 + mi][ni] = MFMA16(af[mi], bf[ni], acc[mh * 2 + mi][ni]);
      __builtin_amdgcn_s_setprio(0);
      asm volatile("s_barrier" ::: "memory");
    }
  }

#pragma unroll
  for (int ni = 0; ni < 4; ni++) {
    const int n = n0 + wc * 64 + ni * 16 + (lane & 15);
    const float bb = bo[n];
#pragma unroll
    for (int mi = 0; mi < 4; mi++) {
      const int mb = m0 + wr * 64 + mi * 16 + ((lane >> 4) << 2);
#pragma unroll
      for (int r = 0; r < 4; r++)
        out[(size_t)(mb + r) * 1024 + n] = acc[mi][ni][r] + bb;
    }
  }
}

extern "C" void kernel_launch(void* const* d_in, const int* in_sizes, int n_in,
                              void* d_out, int out_size, void* d_ws, size_t ws_size,
                              hipStream_t stream) {
  const float* hs = (const float*)d_in[0];
  const float* tau = (const float*)d_in[1];
  const float* delta = (const float*)d_in[2];
  const float* Wq = (const float*)d_in[3];
  const float* bq = (const float*)d_in[4];
  const float* Wk = (const float*)d_in[5];
  const float* bk = (const float*)d_in[6];
  const float* Wv = (const float*)d_in[7];
  const float* bv = (const float*)d_in[8];
  const float* Wo = (const float*)d_in[9];
  const float* bo = (const float*)d_in[10];
  float* out = (float*)d_out;

  u16* ws = (u16*)d_ws;
  u16* hsb  = ws;                   // 4194304
  u16* wqkv = ws + 4194304;         // 3145728 (Wq|Wk|Wv)
  u16* wob  = ws + 7340032;         // 1048576
  u16* qg   = ws + 8388608;         // 4194304
  u16* kg   = ws + 12582912;        // 4194304
  u16* vTg  = ws + 16777216;        // 4194304
  u16* ctxg = ws + 20971520;        // 4194304
  float* dsc = (float*)(ws + 25165824);  // 4096 floats

  cast_all<<<8192, 256, 0, stream>>>(hs, Wq, Wk, Wv, Wo, delta, ws, dsc);

  gemm_qkv192<<<dim3(16, 16), 512, 0, stream>>>(hsb, wqkv, bq, bk, bv, tau, qg, kg, vTg);
  attn<<<256, 512, 0, stream>>>(qg, kg, vTg, dsc, ctxg);
  gemm_out128<<<dim3(8, 32), 256, 0, stream>>>(ctxg, wob, bo, out);
}

// Round 12
// 132.796 us; speedup vs baseline: 1.6082x; 1.0479x over previous
//
#include <hip/hip_runtime.h>

#define B_ 2
#define L_ 2048
#define H_ 1024
#define NH_ 16
#define HD_ 64

using short8 = __attribute__((__ext_vector_type__(8))) short;
using f32x4 = __attribute__((__ext_vector_type__(4))) float;
using f32x16 = __attribute__((__ext_vector_type__(16))) float;
typedef unsigned short u16;
typedef unsigned int u32;

__device__ __forceinline__ u16 f2bf(float f) {
  union { float f; unsigned u; } x{f};
  unsigned u = x.u;
  u = u + 0x7FFFu + ((u >> 16) & 1u);  // round-to-nearest-even
  return (u16)(u >> 16);
}

__device__ __forceinline__ void gld16(const void* g, void* l) {
  __builtin_amdgcn_global_load_lds(
      (const __attribute__((address_space(1))) void*)g,
      (__attribute__((address_space(3))) void*)l, 16, 0, 0);
}

#define MFMA16(a, b, c) __builtin_amdgcn_mfma_f32_16x16x32_bf16((a), (b), (c), 0, 0, 0)
#define MFMA32(a, b, c) __builtin_amdgcn_mfma_f32_32x32x16_bf16((a), (b), (c), 0, 0, 0)

// ---------------- fused cast: hs|Wq|Wk|Wv|Wo -> bf16 (contiguous dst), delta prescale -> bf16 ----------------
__global__ void cast_all(const float* __restrict__ hs, const float* __restrict__ Wq,
                         const float* __restrict__ Wk, const float* __restrict__ Wv,
                         const float* __restrict__ Wo, const float* __restrict__ delta,
                         u16* __restrict__ dst, u16* __restrict__ dscb) {
  const int t = blockIdx.x * 256 + threadIdx.x;
  const int i = t * 4;
  const float* src;
  int off;
  if (i < 4194304) {
    src = hs; off = i;
  } else {
    const int j = i - 4194304;
    const int w = j >> 20;
    off = j & 1048575;
    src = (w == 0) ? Wq : (w == 1) ? Wk : (w == 2) ? Wv : Wo;
  }
  float4 v = *(const float4*)(src + off);
  *(ushort4*)(dst + i) = make_ushort4(f2bf(v.x), f2bf(v.y), f2bf(v.z), f2bf(v.w));
  if (t < 4096) dscb[t] = f2bf(delta[t] * 0.18033688011112042f);  // 0.125*log2(e), bf16
}

// ---------------- QKV GEMM, 256x192 tile, counted-vmcnt pipeline, 256 blocks (R11, unchanged) ----------------
__global__ __launch_bounds__(512) void gemm_qkv192(
    const u16* __restrict__ A, const u16* __restrict__ W,
    const float* __restrict__ bq, const float* __restrict__ bk, const float* __restrict__ bv,
    const float* __restrict__ tau,
    u16* __restrict__ qg, u16* __restrict__ kg, u16* __restrict__ vTg) {
  __shared__ u16 As[2][256 * 64];   // 64 KB
  __shared__ u16 Bs[2][192 * 64];   // 48 KB
  const int tid = threadIdx.x;
  const int lane = tid & 63;
  const int wid = tid >> 6;
  const int wr = wid >> 2;
  const int wc = wid & 3;
  const int orig = blockIdx.y * 16 + blockIdx.x;
  const int wg = (orig & 7) * 32 + (orig >> 3);
  const int m0 = (wg & 15) * 256;
  const int n0 = (wg >> 4) * 192;

  const int srow = tid >> 3;
  const int sg = tid & 7;

#define STAGEQ(slot, t_)                                                                \
  {                                                                                     \
    const int kt64 = (t_) * 64;                                                         \
    _Pragma("unroll") for (int li = 0; li < 4; li++) {                                  \
      const int row = li * 64 + srow;                                                   \
      const int gsrc = sg ^ (row & 7);                                                  \
      gld16(A + (size_t)(m0 + row) * 1024 + kt64 + gsrc * 8,                            \
            (char*)As[slot] + li * 8192 + wid * 1024 + lane * 16);                      \
    }                                                                                   \
    _Pragma("unroll") for (int li = 0; li < 3; li++) {                                  \
      const int row = li * 64 + srow;                                                   \
      const int gsrc = sg ^ (row & 7);                                                  \
      gld16(W + (size_t)(n0 + row) * 1024 + kt64 + gsrc * 8,                            \
            (char*)Bs[slot] + li * 8192 + wid * 1024 + lane * 16);                      \
    }                                                                                   \
  }

  f32x4 acc[8][3] = {};

  STAGEQ(0, 0);
  STAGEQ(1, 1);

  for (int t = 0; t < 16; t++) {
    if (t >= 1 && t + 1 < 16) STAGEQ((t + 1) & 1, t + 1);
    if (t + 1 < 16) {
      asm volatile("s_waitcnt vmcnt(7)" ::: "memory");
    } else {
      asm volatile("s_waitcnt vmcnt(0)" ::: "memory");
    }
    asm volatile("s_barrier" ::: "memory");
    const u16* Ab = As[t & 1];
    const u16* Bb = Bs[t & 1];
    short8 bf[3];
#pragma unroll
    for (int q = 0; q < 4; q++) {
      const int mh = q & 1, ks = q >> 1;
      const int g0 = ks * 4 + (lane >> 4);
      if (mh == 0) {
#pragma unroll
        for (int ni = 0; ni < 3; ni++) {
          const int r = wc * 48 + ni * 16 + (lane & 15);
          bf[ni] = *(const short8*)((const char*)Bb + r * 128 + ((g0 ^ (r & 7)) << 4));
        }
      }
      short8 af[4];
#pragma unroll
      for (int mi = 0; mi < 4; mi++) {
        const int r = wr * 128 + (mh * 4 + mi) * 16 + (lane & 15);
        af[mi] = *(const short8*)((const char*)Ab + r * 128 + ((g0 ^ (r & 7)) << 4));
      }
      __builtin_amdgcn_s_setprio(1);
#pragma unroll
      for (int mi = 0; mi < 4; mi++)
#pragma unroll
        for (int ni = 0; ni < 3; ni++)
          acc[mh * 4 + mi][ni] = MFMA16(af[mi], bf[ni], acc[mh * 4 + mi][ni]);
      __builtin_amdgcn_s_setprio(0);
      asm volatile("s_barrier" ::: "memory");
    }
  }

  const int b_blk = m0 >> 11;
  const float tauv = tau[b_blk] * 0.18033688011112042f;
#pragma unroll
  for (int ni = 0; ni < 3; ni++) {
    const int nbase = n0 + wc * 48 + ni * 16;
    const int which = nbase >> 10;
    const int n = nbase + (lane & 15);
    const int nn = n & 1023;
    const int h = nn >> 6, d = nn & 63;
    const float* bias = which == 0 ? bq : (which == 1 ? bk : bv);
    const float bb = bias[nn];
    const float scl = which == 0 ? tauv : 1.0f;
#pragma unroll
    for (int mi = 0; mi < 8; mi++) {
      const int mb = m0 + wr * 128 + mi * 16 + ((lane >> 4) << 2);
      const int b = mb >> 11;
      const int lq = mb & 2047;
      if (which == 2) {
        ushort4 pk = make_ushort4(f2bf(acc[mi][ni][0] + bb), f2bf(acc[mi][ni][1] + bb),
                                  f2bf(acc[mi][ni][2] + bb), f2bf(acc[mi][ni][3] + bb));
        *(ushort4*)&vTg[((size_t)(b * NH_ + h) * HD_ + d) * L_ + lq] = pk;
      } else {
        u16* dst = which == 0 ? qg : kg;
#pragma unroll
        for (int r = 0; r < 4; r++)
          dst[((size_t)(b * NH_ + h) * L_ + lq + r) * HD_ + d] = f2bf((acc[mi][ni][r] + bb) * scl);
      }
    }
  }
}

// ---------------- flash attention, 8-wave blocks, 3-buffer ring + QK prefetch, delta-via-MFMA ----------------
__global__ __launch_bounds__(512) void attn(
    const u16* __restrict__ qg, const u16* __restrict__ kg, const u16* __restrict__ vTg,
    const u16* __restrict__ dscb, u16* __restrict__ ctxg) {
  __shared__ u16 lds[3][8192];
  const int tid = threadIdx.x;
  const int lane = tid & 63;
  const int wv = tid >> 6;   // 0..7
  const int lane31 = lane & 31;
  const int hi = lane >> 5;
  const int orig = blockIdx.x;
  const int wgid = (orig & 7) * 32 + (orig >> 3);
  const int bh = wgid >> 3;
  const int qblk = wgid & 7;
  const int b = bh >> 4;
  const int h = bh & 15;
  const int q0 = qblk * 256 + wv * 32;
  const u16* qb = qg + (size_t)bh * L_ * HD_;
  const u16* kb = kg + (size_t)bh * L_ * HD_;
  const u16* vb = vTg + (size_t)bh * HD_ * L_;
  const u16* dbb = dscb + (size_t)b * L_;

  short8 qf[4];
#pragma unroll
  for (int ks = 0; ks < 4; ks++)
    qf[ks] = *(const short8*)&qb[(size_t)(q0 + lane31) * 64 + ks * 16 + hi * 8];

  // A-operand ones (row d=0): for accl denominator MFMA
  union U8 { u32 u[4]; short8 s; };
  U8 onesu;
  const u32 ow = (lane31 == 0) ? 0x3F803F80u : 0u;
  onesu.u[0] = ow; onesu.u[1] = ow; onesu.u[2] = ow; onesu.u[3] = ow;
  const short8 onesf = onesu.s;
  // B-operand ones (k=0 row of B = 1 for every q column): for delta MFMA
  U8 onesbu;
  onesbu.u[0] = (hi == 0) ? 0x00003F80u : 0u;
  onesbu.u[1] = 0; onesbu.u[2] = 0; onesbu.u[3] = 0;
  const short8 onesB = onesbu.s;

  f32x16 acc[2] = {};
  f32x16 accl = {};
  float mrun = -__builtin_inff();

#define STAGE(bp_, j0)                                                                    \
  {                                                                                       \
    u16* bp = (bp_);                                                                      \
    {                                                                                     \
      const int kt = wv >> 2, ks = wv & 3;                                                \
      gld16(kb + (size_t)((j0) + kt * 32 + lane31) * 64 + ks * 16 + hi * 8,               \
            bp + wv * 512 + lane * 8);                                                    \
    }                                                                                     \
    {                                                                                     \
      const int kt = wv >> 2, dt = (wv >> 1) & 1, ks2 = wv & 1;                           \
      gld16(vb + (size_t)(dt * 32 + lane31) * L_ + (j0) + kt * 32 + ks2 * 16 + hi * 8,    \
            bp + (8 + wv) * 512 + lane * 8);                                              \
    }                                                                                     \
  }

// QK^T + delta for one 64-key tile: S^T[key][q] = K.Q^T + delta[key]*ones[q]
#define QK64(bp_, j_, sA_, sB_)                                                           \
  {                                                                                       \
    const u16* bp = (bp_);                                                                \
    U8 df0, df1;                                                                          \
    df0.u[0] = (hi == 0) ? (u32)dbb[(j_) + lane31] : 0u;                                  \
    df0.u[1] = 0; df0.u[2] = 0; df0.u[3] = 0;                                             \
    df1.u[0] = (hi == 0) ? (u32)dbb[(j_) + 32 + lane31] : 0u;                             \
    df1.u[1] = 0; df1.u[2] = 0; df1.u[3] = 0;                                             \
    __builtin_amdgcn_s_setprio(1);                                                        \
    sA_ = MFMA32(df0.s, onesB, sA_);                                                      \
    sB_ = MFMA32(df1.s, onesB, sB_);                                                      \
    _Pragma("unroll") for (int ks = 0; ks < 4; ks++) {                                    \
      short8 kf0 = *(const short8*)&bp[(0 * 4 + ks) * 512 + lane * 8];                    \
      short8 kf1 = *(const short8*)&bp[(1 * 4 + ks) * 512 + lane * 8];                    \
      sA_ = MFMA32(kf0, qf[ks], sA_);                                                     \
      sB_ = MFMA32(kf1, qf[ks], sB_);                                                     \
    }                                                                                     \
    __builtin_amdgcn_s_setprio(0);                                                        \
  }

  STAGE(lds[0], 0);
  STAGE(lds[1], 64);
  __syncthreads();

  f32x16 sp0 = {}, sp1 = {};
  QK64(lds[0], 0, sp0, sp1);

  int cur = 0, nxt = 1, fut = 2;
  for (int t = 0; t < 32; t++) {
    const int j0 = t * 64;
    if (t + 2 < 32) STAGE(lds[fut], j0 + 128);
    // QK+delta prefetch for tile t+1 (MFMA pipe; overlaps softmax below)
    f32x16 sn0 = {}, sn1 = {};
    if (t + 1 < 32) QK64(lds[nxt], j0 + 64, sn0, sn1);

    // ---- joint max over 64 keys (v_max3-friendly tree) ----
    float tm[4];
#pragma unroll
    for (int r = 0; r < 4; r++) {
      float a0 = fmaxf(fmaxf(sp0[r], sp0[4 + r]), fmaxf(sp0[8 + r], sp0[12 + r]));
      float a1 = fmaxf(fmaxf(sp1[r], sp1[4 + r]), fmaxf(sp1[8 + r], sp1[12 + r]));
      tm[r] = fmaxf(a0, a1);
    }
    float pmax = fmaxf(fmaxf(tm[0], tm[1]), fmaxf(tm[2], tm[3]));
    pmax = fmaxf(pmax, __shfl_xor(pmax, 32));
    if (!__all(pmax - mrun <= 11.5f)) {
      float mnew = fmaxf(mrun, pmax);
      float al = __builtin_amdgcn_exp2f(mrun - mnew);
      mrun = mnew;
      accl[0] *= al;
#pragma unroll
      for (int dt = 0; dt < 2; dt++)
#pragma unroll
        for (int r = 0; r < 16; r++) acc[dt][r] *= al;
    }

    const u16* bp = lds[cur];
    // ---- kt=0: exp, pack, PV (VALU of kt=1 below overlaps these MFMAs) ----
#pragma unroll
    for (int r = 0; r < 16; r++) sp0[r] = __builtin_amdgcn_exp2f(sp0[r] - mrun);
    u32 pk0[8];
#pragma unroll
    for (int i = 0; i < 8; i++)
      asm("v_cvt_pk_bf16_f32 %0, %1, %2" : "=v"(pk0[i]) : "v"(sp0[2 * i]), "v"(sp0[2 * i + 1]));
    asm volatile("v_permlane32_swap_b32 %0, %1" : "+v"(pk0[0]), "+v"(pk0[2]));
    asm volatile("v_permlane32_swap_b32 %0, %1" : "+v"(pk0[1]), "+v"(pk0[3]));
    asm volatile("v_permlane32_swap_b32 %0, %1" : "+v"(pk0[4]), "+v"(pk0[6]));
    asm volatile("v_permlane32_swap_b32 %0, %1" : "+v"(pk0[5]), "+v"(pk0[7]));
    __builtin_amdgcn_s_setprio(1);
#pragma unroll
    for (int ks2 = 0; ks2 < 2; ks2++) {
      U8 pf;
      pf.u[0] = pk0[ks2 * 4 + 0]; pf.u[1] = pk0[ks2 * 4 + 1];
      pf.u[2] = pk0[ks2 * 4 + 2]; pf.u[3] = pk0[ks2 * 4 + 3];
#pragma unroll
      for (int dt = 0; dt < 2; dt++) {
        short8 vf = *(const short8*)&bp[(8 + 0 * 4 + dt * 2 + ks2) * 512 + lane * 8];
        acc[dt] = MFMA32(vf, pf.s, acc[dt]);
      }
      accl = MFMA32(onesf, pf.s, accl);
    }
    __builtin_amdgcn_s_setprio(0);
    // ---- kt=1: exp, pack, PV ----
#pragma unroll
    for (int r = 0; r < 16; r++) sp1[r] = __builtin_amdgcn_exp2f(sp1[r] - mrun);
    u32 pk1[8];
#pragma unroll
    for (int i = 0; i < 8; i++)
      asm("v_cvt_pk_bf16_f32 %0, %1, %2" : "=v"(pk1[i]) : "v"(sp1[2 * i]), "v"(sp1[2 * i + 1]));
    asm volatile("v_permlane32_swap_b32 %0, %1" : "+v"(pk1[0]), "+v"(pk1[2]));
    asm volatile("v_permlane32_swap_b32 %0, %1" : "+v"(pk1[1]), "+v"(pk1[3]));
    asm volatile("v_permlane32_swap_b32 %0, %1" : "+v"(pk1[4]), "+v"(pk1[6]));
    asm volatile("v_permlane32_swap_b32 %0, %1" : "+v"(pk1[5]), "+v"(pk1[7]));
    __builtin_amdgcn_s_setprio(1);
#pragma unroll
    for (int ks2 = 0; ks2 < 2; ks2++) {
      U8 pf;
      pf.u[0] = pk1[ks2 * 4 + 0]; pf.u[1] = pk1[ks2 * 4 + 1];
      pf.u[2] = pk1[ks2 * 4 + 2]; pf.u[3] = pk1[ks2 * 4 + 3];
#pragma unroll
      for (int dt = 0; dt < 2; dt++) {
        short8 vf = *(const short8*)&bp[(8 + 1 * 4 + dt * 2 + ks2) * 512 + lane * 8];
        acc[dt] = MFMA32(vf, pf.s, acc[dt]);
      }
      accl = MFMA32(onesf, pf.s, accl);
    }
    __builtin_amdgcn_s_setprio(0);
    __syncthreads();
    sp0 = sn0; sp1 = sn1;
    const int tmp = cur; cur = nxt; nxt = fut; fut = tmp;
  }

  u16* tw = (u16*)lds + wv * 2048;
  const float l0 = accl[0];
  const float l1 = __shfl_xor(l0, 32);
  const float inv = 1.0f / (hi ? l1 : l0);
#pragma unroll
  for (int dt = 0; dt < 2; dt++)
#pragma unroll
    for (int g = 0; g < 4; g++) {
      ushort4 w4 = make_ushort4(f2bf(acc[dt][g * 4 + 0] * inv), f2bf(acc[dt][g * 4 + 1] * inv),
                                f2bf(acc[dt][g * 4 + 2] * inv), f2bf(acc[dt][g * 4 + 3] * inv));
      const int d0 = dt * 32 + g * 8 + hi * 4;
      const int byte = (lane31 * 128 + d0 * 2) ^ ((lane31 & 15) << 3);
      *(ushort4*)((char*)tw + byte) = w4;
    }
  asm volatile("s_waitcnt lgkmcnt(0)" ::: "memory");
  const size_t obase = ((size_t)b * L_ + q0) * 1024 + h * 64;
#pragma unroll
  for (int i = 0; i < 16; i++) {
    const int qr = 2 * i + hi;
    const int byte = (qr * 128 + lane31 * 4) ^ ((qr & 15) << 3);
    const u32 val = *(const u32*)((const char*)tw + byte);
    *(u32*)&ctxg[obase + (size_t)qr * 1024 + lane31 * 2] = val;
  }
}

// ---------------- output GEMM, 128x128 tile, counted-vmcnt pipeline (R11, unchanged) ----------------
__global__ __launch_bounds__(256) void gemm_out128(
    const u16* __restrict__ A, const u16* __restrict__ W,
    const float* __restrict__ bo, float* __restrict__ out) {
  __shared__ u16 As[2][128 * 64];
  __shared__ u16 Bs[2][128 * 64];
  const int tid = threadIdx.x;
  const int lane = tid & 63;
  const int wid = tid >> 6;
  const int wr = wid >> 1;
  const int wc = wid & 1;
  const int orig = blockIdx.y * 8 + blockIdx.x;
  const int wg = (orig & 7) * 32 + (orig >> 3);
  const int m0 = (wg & 31) * 128;
  const int n0 = (wg >> 5) * 128;

  const int srow = tid >> 3;
  const int sg = tid & 7;

#define STAGEO(slot, t_)                                                                \
  {                                                                                     \
    const int kt64 = (t_) * 64;                                                         \
    _Pragma("unroll") for (int li = 0; li < 4; li++) {                                  \
      const int row = li * 32 + srow;                                                   \
      const int gsrc = sg ^ (row & 7);                                                  \
      gld16(A + (size_t)(m0 + row) * 1024 + kt64 + gsrc * 8,                            \
            (char*)As[slot] + li * 4096 + wid * 1024 + lane * 16);                      \
      gld16(W + (size_t)(n0 + row) * 1024 + kt64 + gsrc * 8,                            \
            (char*)Bs[slot] + li * 4096 + wid * 1024 + lane * 16);                      \
    }                                                                                   \
  }

  f32x4 acc[4][4] = {};

  STAGEO(0, 0);
  STAGEO(1, 1);

  for (int t = 0; t < 16; t++) {
    if (t >= 1 && t + 1 < 16) STAGEO((t + 1) & 1, t + 1);
    if (t + 1 < 16) {
      asm volatile("s_waitcnt vmcnt(8)" ::: "memory");
    } else {
      asm volatile("s_waitcnt vmcnt(0)" ::: "memory");
    }
    asm volatile("s_barrier" ::: "memory");
    const u16* Ab = As[t & 1];
    const u16* Bb = Bs[t & 1];
    short8 bf[4];
#pragma unroll
    for (int q = 0; q < 4; q++) {
      const int mh = q & 1, ks = q >> 1;
      const int g0 = ks * 4 + (lane >> 4);
      if (mh == 0) {
#pragma unroll
        for (int ni = 0; ni < 4; ni++) {
          const int r = wc * 64 + ni * 16 + (lane & 15);
          bf[ni] = *(const short8*)((const char*)Bb + r * 128 + ((g0 ^ (r & 7)) << 4));
        }
      }
      short8 af[2];
#pragma unroll
      for (int mi = 0; mi < 2; mi++) {
        const int r = wr * 64 + (mh * 2 + mi) * 16 + (lane & 15);
        af[mi] = *(const short8*)((const char*)Ab + r * 128 + ((g0 ^ (r & 7)) << 4));
      }
      __builtin_amdgcn_s_setprio(1);
#pragma unroll
      for (int mi = 0; mi < 2; mi++)
#pragma unroll
        for (int ni = 0; ni < 4; ni++)
          acc[mh * 2 + mi][ni] = MFMA16(af[mi], bf[ni], acc[mh * 2 + mi][ni]);
      __builtin_amdgcn_s_setprio(0);
      asm volatile("s_barrier" ::: "memory");
    }
  }

#pragma unroll
  for (int ni = 0; ni < 4; ni++) {
    const int n = n0 + wc * 64 + ni * 16 + (lane & 15);
    const float bb = bo[n];
#pragma unroll
    for (int mi = 0; mi < 4; mi++) {
      const int mb = m0 + wr * 64 + mi * 16 + ((lane >> 4) << 2);
#pragma unroll
      for (int r = 0; r < 4; r++)
        out[(size_t)(mb + r) * 1024 + n] = acc[mi][ni][r] + bb;
    }
  }
}

extern "C" void kernel_launch(void* const* d_in, const int* in_sizes, int n_in,
                              void* d_out, int out_size, void* d_ws, size_t ws_size,
                              hipStream_t stream) {
  const float* hs = (const float*)d_in[0];
  const float* tau = (const float*)d_in[1];
  const float* delta = (const float*)d_in[2];
  const float* Wq = (const float*)d_in[3];
  const float* bq = (const float*)d_in[4];
  const float* Wk = (const float*)d_in[5];
  const float* bk = (const float*)d_in[6];
  const float* Wv = (const float*)d_in[7];
  const float* bv = (const float*)d_in[8];
  const float* Wo = (const float*)d_in[9];
  const float* bo = (const float*)d_in[10];
  float* out = (float*)d_out;

  u16* ws = (u16*)d_ws;
  u16* hsb  = ws;                   // 4194304
  u16* wqkv = ws + 4194304;         // 3145728 (Wq|Wk|Wv)
  u16* wob  = ws + 7340032;         // 1048576
  u16* qg   = ws + 8388608;         // 4194304
  u16* kg   = ws + 12582912;        // 4194304
  u16* vTg  = ws + 16777216;        // 4194304
  u16* ctxg = ws + 20971520;        // 4194304
  u16* dscb = ws + 25165824;        // 4096 bf16

  cast_all<<<8192, 256, 0, stream>>>(hs, Wq, Wk, Wv, Wo, delta, ws, dscb);

  gemm_qkv192<<<dim3(16, 16), 512, 0, stream>>>(hsb, wqkv, bq, bk, bv, tau, qg, kg, vTg);
  attn<<<256, 512, 0, stream>>>(qg, kg, vTg, dscb, ctxg);
  gemm_out128<<<dim3(8, 32), 256, 0, stream>>>(ctxg, wob, bo, out);
}